// Round 11
// baseline (461.997 us; speedup 1.0000x reference)
//
#include <hip/hip_runtime.h>
#include <cstddef>

#define LN_EPS 1e-5f

typedef unsigned short u16;
typedef short short8 __attribute__((ext_vector_type(8)));
typedef float f32x4 __attribute__((ext_vector_type(4)));

__device__ __forceinline__ u16 f2bf(float f) {
    unsigned int u = __float_as_uint(f);
    u = (u + 0x7FFFu + ((u >> 16) & 1u)) >> 16;
    return (u16)u;
}
__device__ __forceinline__ float bf2f(u16 h) {
    return __uint_as_float((unsigned int)h << 16);
}
// packed RNE f32x2 -> bf16x2 (lo = a, hi = b)
__device__ __forceinline__ unsigned int pk_bf16(float a, float b) {
    unsigned int r;
    asm("v_cvt_pk_bf16_f32 %0, %1, %2" : "=v"(r) : "v"(a), "v"(b));
    return r;
}

// ---------------------------------------------------------------------------
// Multi-tensor fp32 -> bf16 convert (weights + inputs), one launch.
// ---------------------------------------------------------------------------
struct CvtDesc {
    const float* src[16];
    u16* dst[16];
    int n4[16];
};
__global__ __launch_bounds__(256) void cvt_multi(CvtDesc d) {
    const int t = blockIdx.x * 256 + threadIdx.x;
    const int i = blockIdx.y;
    if (t >= d.n4[i]) return;
    const float4 v = ((const float4*)d.src[i])[t];
    ushort4 o;
    o.x = f2bf(v.x); o.y = f2bf(v.y); o.z = f2bf(v.z); o.w = f2bf(v.w);
    ((ushort4*)d.dst[i])[t] = o;
}

// ---------------------------------------------------------------------------
// GROUPED bf16 MFMA NT GEMM, templated on tile (64x64 or 128x128), BK=64.
// Big GEMMs (QKV/KV/FFN-up) use the 128 tile: 32 MFMAs per wave per barrier
// pair vs 8 for the 64 tile (4x MFMA density). Small/K-heavy shapes keep 64
// for block count. Group found by prefix-offset scan (block-uniform).
// C = scale*(A@B^T + bias) + res1 (+relu). Outputs fp32 and/or bf16.
// ---------------------------------------------------------------------------
struct GGDesc {
    const u16* A[6]; const u16* B[6];
    float* Cf[6]; u16* Ch[6];
    const float* bias[6]; const float* res1[6];
    int lda[6], ldb[6], ldc[6], K[6], relu[6], nt[6], off[6];
    float scale[6];
    int ngroups;
};
template<int BM, int BN>
__global__ __launch_bounds__(256) void gg_gemm(GGDesc d) {
    constexpr int MF = BM / 32;
    constexpr int NF = BN / 32;
    constexpr int MP = BM / 32;
    constexpr int NP = BN / 32;
    __shared__ u16 As[BM * 72];
    __shared__ u16 Bs[BN * 72];

    int g = 0;
    const int bid = blockIdx.x;
    while (g + 1 < d.ngroups && bid >= d.off[g + 1]) ++g;
    const int local = bid - d.off[g];
    const int m0 = (local / d.nt[g]) * BM;
    const int n0 = (local % d.nt[g]) * BN;

    const u16* __restrict__ A = d.A[g];
    const u16* __restrict__ B = d.B[g];
    const int lda = d.lda[g], ldb = d.ldb[g], ldc = d.ldc[g];
    const int K = d.K[g], relu = d.relu[g];
    const float scale = d.scale[g];

    const int tid = threadIdx.x;
    const int wave = tid >> 6, lane = tid & 63;
    const int wm = wave >> 1, wn = wave & 1;

    f32x4 acc[MF][NF];
#pragma unroll
    for (int mf = 0; mf < MF; ++mf)
#pragma unroll
        for (int nf = 0; nf < NF; ++nf) acc[mf][nf] = (f32x4){0.f, 0.f, 0.f, 0.f};

    const int ar = tid >> 3, ac = (tid & 7) * 8;   // 32 rows x 64 cols per pass
    const int ml = lane & 15, kq = lane >> 4;

    short8 aN[MP], bN[NP];
#pragma unroll
    for (int c = 0; c < MP; ++c)
        aN[c] = *(const short8*)&A[(size_t)(m0 + ar + c * 32) * lda + ac];
#pragma unroll
    for (int c = 0; c < NP; ++c)
        bN[c] = *(const short8*)&B[(size_t)(n0 + ar + c * 32) * ldb + ac];

    for (int k0 = 0; k0 < K; k0 += 64) {
        short8 aS[MP], bS[NP];
#pragma unroll
        for (int c = 0; c < MP; ++c) aS[c] = aN[c];
#pragma unroll
        for (int c = 0; c < NP; ++c) bS[c] = bN[c];
        if (k0 + 64 < K) {
#pragma unroll
            for (int c = 0; c < MP; ++c)
                aN[c] = *(const short8*)&A[(size_t)(m0 + ar + c * 32) * lda + k0 + 64 + ac];
#pragma unroll
            for (int c = 0; c < NP; ++c)
                bN[c] = *(const short8*)&B[(size_t)(n0 + ar + c * 32) * ldb + k0 + 64 + ac];
        }
        __syncthreads();
#pragma unroll
        for (int c = 0; c < MP; ++c) *(short8*)&As[(ar + c * 32) * 72 + ac] = aS[c];
#pragma unroll
        for (int c = 0; c < NP; ++c) *(short8*)&Bs[(ar + c * 32) * 72 + ac] = bS[c];
        __syncthreads();

        short8 af0[MF], af1[MF], bf0[NF], bf1[NF];
#pragma unroll
        for (int mf = 0; mf < MF; ++mf) {
            const int base = (wm * (BM / 2) + mf * 16 + ml) * 72 + kq * 8;
            af0[mf] = *(const short8*)&As[base];
            af1[mf] = *(const short8*)&As[base + 32];
        }
#pragma unroll
        for (int nf = 0; nf < NF; ++nf) {
            const int base = (wn * (BN / 2) + nf * 16 + ml) * 72 + kq * 8;
            bf0[nf] = *(const short8*)&Bs[base];
            bf1[nf] = *(const short8*)&Bs[base + 32];
        }
#pragma unroll
        for (int mf = 0; mf < MF; ++mf)
#pragma unroll
            for (int nf = 0; nf < NF; ++nf) {
                acc[mf][nf] = __builtin_amdgcn_mfma_f32_16x16x32_bf16(
                    af0[mf], bf0[nf], acc[mf][nf], 0, 0, 0);
                acc[mf][nf] = __builtin_amdgcn_mfma_f32_16x16x32_bf16(
                    af1[mf], bf1[nf], acc[mf][nf], 0, 0, 0);
            }
    }

    float* __restrict__ Cf = d.Cf[g];
    u16* __restrict__ Ch = d.Ch[g];
    const float* __restrict__ bias = d.bias[g];
    const float* __restrict__ res1 = d.res1[g];
    const int rq = lane >> 4;
#pragma unroll
    for (int mf = 0; mf < MF; ++mf)
#pragma unroll
        for (int nf = 0; nf < NF; ++nf) {
            const int col = n0 + wn * (BN / 2) + nf * 16 + ml;
            const float bv = bias ? bias[col] : 0.f;
#pragma unroll
            for (int r = 0; r < 4; ++r) {
                const int row = m0 + wm * (BM / 2) + mf * 16 + rq * 4 + r;
                float v = scale * (acc[mf][nf][r] + bv);
                const size_t idx = (size_t)row * ldc + col;
                if (res1) v += res1[idx];
                if (relu) v = fmaxf(v, 0.f);
                if (Cf) Cf[idx] = v;
                if (Ch) Ch[idx] = f2bf(v);
            }
        }
}

// ---------------------------------------------------------------------------
// GROUPED V transpose (within-64 permuted layout; see attn_flash64g).
// ---------------------------------------------------------------------------
struct VTDesc {
    const u16* V[3]; u16* vT[3]; int ldv[3], S[3], off[3]; int ng;
};
__global__ __launch_bounds__(256) void vtrans_g(VTDesc d) {
    __shared__ u16 Vs[64 * 72];
    int g = 0;
    const int bid = blockIdx.x;
    while (g + 1 < d.ng && bid >= d.off[g + 1]) ++g;
    const int local = bid - d.off[g];
    const int S = d.S[g], ldv = d.ldv[g];
    const int nS = S >> 6;
    const int s0 = (local % nS) * 64;
    const int bh = local / nS, b = bh & 1, h = bh >> 1;
    const u16* __restrict__ V = d.V[g];
    u16* __restrict__ vT = d.vT[g];
    const int tid = threadIdx.x;

#pragma unroll
    for (int c = 0; c < 2; ++c) {
        const int idx = tid + c * 256;
        const int sr = idx >> 3, dc = (idx & 7) * 8;
        *(short8*)&Vs[sr * 72 + dc] =
            *(const short8*)&V[(size_t)((s0 + sr) * 2 + b) * ldv + h * 64 + dc];
    }
    __syncthreads();
#pragma unroll
    for (int c = 0; c < 2; ++c) {
        const int idx = tid + c * 256;
        const int dr = idx >> 3, sc = (idx & 7) * 8;
        short8 o;
#pragma unroll
        for (int j = 0; j < 8; ++j) {
            const int p = sc + j;
            o[j] = (short)Vs[((p >> 2) + 16 * (p & 3)) * 72 + dr];
        }
        *(short8*)&vT[(size_t)bh * 64 * S + (size_t)dr * S + s0 + sc] = o;
    }
}

// ---------------------------------------------------------------------------
// GROUPED split-S flash attention (round-8 verified body, descriptor-batched;
// up to 3 independent attentions per launch). Separate merge kernel (stream
// boundary provides cross-block ordering — NO device fences, round-7 lesson).
// ---------------------------------------------------------------------------
struct FADesc {
    const u16* Q[3]; const u16* Kp[3]; const u16* vT[3]; u16* scores[3];
    float* Of[3]; float2* pml[3];
    int ldq[3], ldk[3], L[3], S[3], CS[3], off[3];
    int ng;
};
template<bool NEED_W>
__global__ __launch_bounds__(256) void attn_flash64g(FADesc d) {
    __shared__ u16 Ks[64 * 72];
    __shared__ u16 Vt[64 * 72];
    __shared__ u16 St[4][16 * 72];

    int g = 0;
    const int bid = blockIdx.x;
    while (g + 1 < d.ng && bid >= d.off[g + 1]) ++g;
    int local = bid - d.off[g];
    const int L = d.L[g], S = d.S[g], CS = d.CS[g];
    const int ldq = d.ldq[g], ldk = d.ldk[g];
    const int nx = L >> 6;
    const int bx = local % nx; local /= nx;
    const int bz = local & 15;
    const int chunk = local >> 4;

    const u16* __restrict__ Q = d.Q[g];
    const u16* __restrict__ Kp = d.Kp[g];
    const u16* __restrict__ vT = d.vT[g];
    float* __restrict__ Of = d.Of[g];
    float2* __restrict__ pml = d.pml[g];

    const int tid = threadIdx.x;
    const int wave = tid >> 6, lane = tid & 63;
    const int ml = lane & 15, rq = lane >> 4;
    const int i0 = bx * 64;
    const int bb = bz & 1, hh = bz >> 1;
    const int cs0 = chunk * CS;
    u16* Sb = NEED_W ? d.scores[g] + (size_t)bz * L * S + (size_t)i0 * S : nullptr;
    const u16* Vbase = vT + (size_t)bz * 64 * S;

    const int qrow = i0 + wave * 16 + ml;
    const short8 qf0 = *(const short8*)&Q[(size_t)(qrow * 2 + bb) * ldq + hh * 64 + rq * 8];
    const short8 qf1 = *(const short8*)&Q[(size_t)(qrow * 2 + bb) * ldq + hh * 64 + 32 + rq * 8];

    float mrun[4], lrun[4];
    f32x4 acc[4];
#pragma unroll
    for (int r = 0; r < 4; ++r) {
        mrun[r] = -1e30f; lrun[r] = 0.f;
        acc[r] = (f32x4){0.f, 0.f, 0.f, 0.f};
    }

    const int sr0 = tid >> 3, dc0 = (tid & 7) * 8;
    const int sr1 = (tid + 256) >> 3, dc1 = ((tid + 256) & 7) * 8;

    short8 kr0 = *(const short8*)&Kp[(size_t)((cs0 + sr0) * 2 + bb) * ldk + hh * 64 + dc0];
    short8 kr1 = *(const short8*)&Kp[(size_t)((cs0 + sr1) * 2 + bb) * ldk + hh * 64 + dc1];
    short8 vr0 = *(const short8*)&Vbase[(size_t)sr0 * S + cs0 + dc0];
    short8 vr1 = *(const short8*)&Vbase[(size_t)sr1 * S + cs0 + dc1];

    u16* Sw = St[wave];

    for (int k0 = cs0; k0 < cs0 + CS; k0 += 64) {
        __syncthreads();
        *(short8*)&Ks[sr0 * 72 + dc0] = kr0;
        *(short8*)&Ks[sr1 * 72 + dc1] = kr1;
        *(short8*)&Vt[sr0 * 72 + dc0] = vr0;
        *(short8*)&Vt[sr1 * 72 + dc1] = vr1;
        if (k0 + 64 < cs0 + CS) {
            const int kn = k0 + 64;
            kr0 = *(const short8*)&Kp[(size_t)((kn + sr0) * 2 + bb) * ldk + hh * 64 + dc0];
            kr1 = *(const short8*)&Kp[(size_t)((kn + sr1) * 2 + bb) * ldk + hh * 64 + dc1];
            vr0 = *(const short8*)&Vbase[(size_t)sr0 * S + kn + dc0];
            vr1 = *(const short8*)&Vbase[(size_t)sr1 * S + kn + dc1];
        }
        __syncthreads();

        f32x4 sc[4];
#pragma unroll
        for (int nf = 0; nf < 4; ++nf) {
            const short8 kf0 = *(const short8*)&Ks[(nf * 16 + ml) * 72 + rq * 8];
            const short8 kf1 = *(const short8*)&Ks[(nf * 16 + ml) * 72 + 32 + rq * 8];
            f32x4 s = (f32x4){0.f, 0.f, 0.f, 0.f};
            s = __builtin_amdgcn_mfma_f32_16x16x32_bf16(qf0, kf0, s, 0, 0, 0);
            s = __builtin_amdgcn_mfma_f32_16x16x32_bf16(qf1, kf1, s, 0, 0, 0);
#pragma unroll
            for (int r = 0; r < 4; ++r) s[r] *= 0.125f;
            sc[nf] = s;
        }

        if (NEED_W) {
#pragma unroll
            for (int r = 0; r < 4; ++r) {
                const unsigned int pk0 = pk_bf16(sc[0][r], sc[1][r]);
                const unsigned int pk1 = pk_bf16(sc[2][r], sc[3][r]);
                *(uint2*)&Sb[(size_t)(wave * 16 + rq * 4 + r) * S + k0 + ml * 4] =
                    make_uint2(pk0, pk1);
            }
        }

        float tm[4];
#pragma unroll
        for (int r = 0; r < 4; ++r)
            tm[r] = fmaxf(fmaxf(sc[0][r], sc[1][r]), fmaxf(sc[2][r], sc[3][r]));
#pragma unroll
        for (int mk = 1; mk < 16; mk <<= 1)
#pragma unroll
            for (int r = 0; r < 4; ++r)
                tm[r] = fmaxf(tm[r], __shfl_xor(tm[r], mk));

        float alpha[4], mn[4];
#pragma unroll
        for (int r = 0; r < 4; ++r) {
            mn[r] = fmaxf(mrun[r], tm[r]);
            alpha[r] = __expf(mrun[r] - mn[r]);
            mrun[r] = mn[r];
        }

        float rs[4];
#pragma unroll
        for (int r = 0; r < 4; ++r) {
            const float p0 = __expf(sc[0][r] - mn[r]);
            const float p1 = __expf(sc[1][r] - mn[r]);
            const float p2 = __expf(sc[2][r] - mn[r]);
            const float p3 = __expf(sc[3][r] - mn[r]);
            rs[r] = (p0 + p1) + (p2 + p3);
            const unsigned int pk0 = pk_bf16(p0, p1);
            const unsigned int pk1 = pk_bf16(p2, p3);
            *(uint2*)&Sw[(rq * 4 + r) * 72 + ml * 4] = make_uint2(pk0, pk1);
        }
#pragma unroll
        for (int mk = 1; mk < 16; mk <<= 1)
#pragma unroll
            for (int r = 0; r < 4; ++r)
                rs[r] += __shfl_xor(rs[r], mk);
#pragma unroll
        for (int r = 0; r < 4; ++r)
            lrun[r] = lrun[r] * alpha[r] + rs[r];

#pragma unroll
        for (int df = 0; df < 4; ++df)
#pragma unroll
            for (int r = 0; r < 4; ++r)
                acc[df][r] *= alpha[r];
#pragma unroll
        for (int kc = 0; kc < 2; ++kc) {
            const short8 afr = *(const short8*)&Sw[ml * 72 + kc * 32 + rq * 8];
#pragma unroll
            for (int df = 0; df < 4; ++df) {
                const short8 bfr = *(const short8*)&Vt[(df * 16 + ml) * 72 + kc * 32 + rq * 8];
                acc[df] = __builtin_amdgcn_mfma_f32_16x16x32_bf16(afr, bfr, acc[df], 0, 0, 0);
            }
        }
    }

#pragma unroll
    for (int df = 0; df < 4; ++df)
#pragma unroll
        for (int r = 0; r < 4; ++r) {
            const int i = i0 + wave * 16 + rq * 4 + r;
            Of[((size_t)(chunk * 16 + bz) * L + i) * 64 + df * 16 + ml] = acc[df][r];
        }
    if (ml == 0) {
#pragma unroll
        for (int r = 0; r < 4; ++r)
            pml[(size_t)chunk * 16 * L + (size_t)bz * L + i0 + wave * 16 + rq * 4 + r] =
                make_float2(mrun[r], lrun[r]);
    }
}

// ---------------------------------------------------------------------------
// GROUPED merge of split-S partials. stats written iff stats[g] != null.
// ---------------------------------------------------------------------------
struct MGDesc {
    const float* Of[3]; const float2* pml[3]; u16* att[3]; float2* stats[3];
    int L[3], nch[3], off[3]; int ng;
};
__global__ __launch_bounds__(256) void attn_merge_g(MGDesc d) {
    int gg = 0;
    const int bid = blockIdx.x;
    while (gg + 1 < d.ng && bid >= d.off[gg + 1]) ++gg;
    const int local = bid - d.off[gg];
    const int L = d.L[gg], nchunks = d.nch[gg];
    const float* __restrict__ Of = d.Of[gg];
    const float2* __restrict__ pml = d.pml[gg];

    const int tid = threadIdx.x;
    const int grow = local * 4 + (tid >> 6);
    const int dcol = tid & 63;
    const int bz = grow / L, i = grow - bz * L;
    const int bb = bz & 1, hh = bz >> 1;

    float M = -1e30f;
    for (int c = 0; c < nchunks; ++c)
        M = fmaxf(M, pml[(size_t)c * 16 * L + grow].x);
    float T = 0.f, O = 0.f;
    for (int c = 0; c < nchunks; ++c) {
        const float2 w2 = pml[(size_t)c * 16 * L + grow];
        const float w = __expf(w2.x - M);
        T += w2.y * w;
        O += w * Of[((size_t)(c * 16 + bz) * L + i) * 64 + dcol];
    }
    const float invT = 1.0f / T;
    d.att[gg][((size_t)i * 2 + bb) * 512 + hh * 64 + dcol] = f2bf(O * invT);
    if (d.stats[gg] && dcol == 0)
        d.stats[gg][(size_t)bz * L + i] = make_float2(M, invT);
}

// ---------------------------------------------------------------------------
// GROUPED head-average + second softmax. probs permuted-within-64; un-permute
// via LDS, coalesced float4 final writes.
// ---------------------------------------------------------------------------
struct AVDesc {
    const u16* P[3]; const float2* st[3]; float* out1[3]; float* out2[3];
    int L[3], S[3], off[3]; int ng;
};
__global__ __launch_bounds__(256) void avg_softmax_g(AVDesc d) {
    __shared__ float red[256];
    __shared__ float stage[2048];
    int g = 0;
    const int bid = blockIdx.x;
    while (g + 1 < d.ng && bid >= d.off[g + 1]) ++g;
    const int local = bid - d.off[g];
    const int L = d.L[g], S = d.S[g];
    const int b = local / L, i = local % L;
    const u16* __restrict__ P = d.P[g];
    const float2* __restrict__ st = d.st[g];
    const size_t LS = (size_t)L * S;
    const int tid = threadIdx.x;
    const bool act = tid * 8 < S;

    float acc[8] = {};
    if (act) {
#pragma unroll
        for (int h = 0; h < 8; ++h) {
            const int bh = h * 2 + b;
            const float2 s = st[(size_t)bh * L + i];
            const short8 r8 = *(const short8*)&P[(size_t)bh * LS + (size_t)i * S + tid * 8];
#pragma unroll
            for (int j = 0; j < 8; ++j)
                acc[j] += __expf(bf2f((u16)r8[j]) - s.x) * s.y;
        }
#pragma unroll
        for (int j = 0; j < 8; ++j) acc[j] *= 0.125f;
    }
    float lmax = -1e30f;
    if (act) {
#pragma unroll
        for (int j = 0; j < 8; ++j) lmax = fmaxf(lmax, acc[j]);
    }
    red[tid] = lmax; __syncthreads();
    for (int s = 128; s; s >>= 1) {
        if (tid < s) red[tid] = fmaxf(red[tid], red[tid + s]);
        __syncthreads();
    }
    const float mx = red[0]; __syncthreads();
    float e[8];
    float ls = 0.f;
    if (act) {
#pragma unroll
        for (int j = 0; j < 8; ++j) { e[j] = __expf(acc[j] - mx); ls += e[j]; }
    }
    red[tid] = ls; __syncthreads();
    for (int s = 128; s; s >>= 1) {
        if (tid < s) red[tid] += red[tid + s];
        __syncthreads();
    }
    const float inv = 1.0f / red[0];
    if (act) {
        const int g64 = (tid >> 3) * 64;
        const int t2 = (tid & 7) * 2;
#pragma unroll
        for (int j = 0; j < 8; ++j) {
            const int c = t2 + (j >> 2) + 16 * (j & 3);
            stage[g64 + c] = e[j] * inv;
        }
    }
    __syncthreads();
    float* out1 = d.out1[g];
    float* out2 = d.out2[g];
    const size_t base = (size_t)local * S;
    for (int idx = tid * 4; idx < S; idx += 1024) {
        const float4 v = *(const float4*)&stage[idx];
        *(float4*)&out1[base + idx] = v;
        if (out2) *(float4*)&out2[base + idx] = v;
    }
}

// ---------------------------------------------------------------------------
// LayerNorm over rows of 512 of (X + optional X2); PAIRED: two groups per
// launch (blockIdx < R0 -> group 0).
// ---------------------------------------------------------------------------
struct LN2Desc {
    const float* X[2]; const float* X2[2];
    const float* gam[2]; const float* bet[2];
    float* Yf[2]; u16* Yb[2]; int R0;
};
__global__ __launch_bounds__(256) void ln512_g(LN2Desc d) {
    __shared__ float red[256];
    const int gi = (blockIdx.x < (unsigned)d.R0) ? 0 : 1;
    const int r = gi ? (blockIdx.x - d.R0) : blockIdx.x;
    const int tid = threadIdx.x;
    const float* xr = d.X[gi] + (size_t)r * 512;
    float x0 = xr[tid], x1 = xr[tid + 256];
    if (d.X2[gi]) {
        const float* x2r = d.X2[gi] + (size_t)r * 512;
        x0 += x2r[tid]; x1 += x2r[tid + 256];
    }
    red[tid] = x0 + x1; __syncthreads();
    for (int st = 128; st; st >>= 1) {
        if (tid < st) red[tid] += red[tid + st];
        __syncthreads();
    }
    const float mean = red[0] * (1.0f / 512.0f); __syncthreads();
    const float d0 = x0 - mean, d1 = x1 - mean;
    red[tid] = d0 * d0 + d1 * d1; __syncthreads();
    for (int st = 128; st; st >>= 1) {
        if (tid < st) red[tid] += red[tid + st];
        __syncthreads();
    }
    const float rstd = rsqrtf(red[0] * (1.0f / 512.0f) + LN_EPS);
    const float y0 = d0 * rstd * d.gam[gi][tid] + d.bet[gi][tid];
    const float y1 = d1 * rstd * d.gam[gi][tid + 256] + d.bet[gi][tid + 256];
    float* yr = d.Yf[gi] + (size_t)r * 512;
    yr[tid] = y0; yr[tid + 256] = y1;
    if (d.Yb[gi]) {
        u16* yb = d.Yb[gi] + (size_t)r * 512;
        yb[tid] = f2bf(y0); yb[tid + 256] = f2bf(y1);
    }
}

// ---------------------------------------------------------------------------
// pair assembly: inverse map + gathers (both destinations in one launch).
// ---------------------------------------------------------------------------
__global__ void init_inv(int* __restrict__ inv) {
    const int i = blockIdx.x * 256 + threadIdx.x;
    if (i < 4096) inv[i] = -1;
}
__global__ void scatter_inv(int* __restrict__ inv, const int* __restrict__ ind, int n) {
    const int i = blockIdx.x * 256 + threadIdx.x;
    if (i < n) inv[ind[i]] = i;
}
__global__ void gather_rows_bf2(
    u16* __restrict__ dst0, u16* __restrict__ dst1,
    const float* __restrict__ spf, const float* __restrict__ ep,
    const int* __restrict__ ind0, const int* __restrict__ ind1,
    const int* __restrict__ inv, int total4)
{
    const int e = blockIdx.x * 256 + threadIdx.x;
    if (e >= total4) return;
    u16* dst = blockIdx.y ? dst1 : dst0;
    const int* ind = blockIdx.y ? ind1 : ind0;
    const int row = e >> 7, c = e & 127;
    const int j = row >> 1, b = row & 1;
    const int idx = ind[j];
    const int iv = inv[idx];
    const float4* src = (iv >= 0) ? (const float4*)(spf + (size_t)(iv * 2 + b) * 512)
                                  : (const float4*)(ep + (size_t)(idx * 2 + b) * 512);
    const float4 v = src[c];
    ushort4 o; o.x = f2bf(v.x); o.y = f2bf(v.y); o.z = f2bf(v.z); o.w = f2bf(v.w);
    ((ushort4*)dst)[e] = o;
}

// ---------------------------------------------------------------------------
extern "C" void kernel_launch(void* const* d_in, const int* in_sizes, int n_in,
                              void* d_out, int out_size, void* d_ws, size_t ws_size,
                              hipStream_t stream)
{
    (void)in_sizes; (void)n_in; (void)out_size; (void)ws_size;

    const float* in_sp = (const float*)d_in[0];
    const float* in_su = (const float*)d_in[1];
    const float* in_ep = (const float*)d_in[2];
    const int* ind_pair = (const int*)d_in[3];
    const int* ind_e2e  = (const int*)d_in[4];
    const int* ind_n2e  = (const int*)d_in[5];
    const float *Wi_sa  = (const float*)d_in[6],  *bi_sa  = (const float*)d_in[7];
    const float *Wo_sa  = (const float*)d_in[8],  *bo_sa  = (const float*)d_in[9];
    const float *Wi_san = (const float*)d_in[10], *bi_san = (const float*)d_in[11];
    const float *Wo_san = (const float*)d_in[12], *bo_san = (const float*)d_in[13];
    const float *Wi_e2e = (const float*)d_in[14], *bi_e2e = (const float*)d_in[15];
    const float *Wo_e2e = (const float*)d_in[16], *bo_e2e = (const float*)d_in[17];
    const float *Wi_n2e = (const float*)d_in[18], *bi_n2e = (const float*)d_in[19];
    const float *Wo_n2e = (const float*)d_in[20], *bo_n2e = (const float*)d_in[21];
    const float *Wi_n2n = (const float*)d_in[22], *bi_n2n = (const float*)d_in[23];
    const float *Wo_n2n = (const float*)d_in[24], *bo_n2n = (const float*)d_in[25];
    const float *W1  = (const float*)d_in[26], *b1f  = (const float*)d_in[27];
    const float *W2  = (const float*)d_in[28], *b2f  = (const float*)d_in[29];
    const float *W1u = (const float*)d_in[30], *b1fu = (const float*)d_in[31];
    const float *W2u = (const float*)d_in[32], *b2fu = (const float*)d_in[33];
    const float *g1  = (const float*)d_in[34], *g1u = (const float*)d_in[35];
    const float *g2  = (const float*)d_in[36], *g3  = (const float*)d_in[37];
    const float *be1 = (const float*)d_in[38], *be1u = (const float*)d_in[39];
    const float *be2 = (const float*)d_in[40], *be3  = (const float*)d_in[41];

    float* Wf = (float*)d_ws;
    size_t of = 0;
    auto af_ = [&](size_t n) { float* p = Wf + of; of += n; return p; };
    float* spf      = af_((size_t)2048 * 512);
    float* suf      = af_((size_t)512 * 512);
    float* tmp0f    = af_((size_t)2048 * 512);
    float* tmp0fu   = af_((size_t)512 * 512);
    float* upn2ef   = af_((size_t)512 * 512);
    float* upn2nf   = af_((size_t)512 * 512);
    float* tmp1f    = af_((size_t)2048 * 512);
    float* tmp1fu   = af_((size_t)512 * 512);
    float2* st_e2e  = (float2*)af_((size_t)2 * 16 * 1024);
    float2* st_n2e  = (float2*)af_((size_t)2 * 16 * 256);
    float2* st_n2n  = (float2*)af_((size_t)2 * 16 * 256);
    float* ofp_sa   = af_((size_t)4 * 16 * 1024 * 64);
    float* ofp_san  = af_((size_t)4 * 16 * 256 * 64);
    float* ofp_e2e  = af_((size_t)4 * 16 * 1024 * 64);
    float* ofp_n2e  = af_((size_t)8 * 16 * 256 * 64);
    float* ofp_n2n  = af_((size_t)4 * 16 * 256 * 64);
    float2* pml_sa  = (float2*)af_((size_t)2 * 4 * 16 * 1024);
    float2* pml_san = (float2*)af_((size_t)2 * 4 * 16 * 256);
    float2* pml_e2e = (float2*)af_((size_t)2 * 4 * 16 * 1024);
    float2* pml_n2e = (float2*)af_((size_t)2 * 8 * 16 * 256);
    float2* pml_n2n = (float2*)af_((size_t)2 * 4 * 16 * 256);

    u16* Wu = (u16*)(Wf + of);
    size_t ou = 0;
    auto au_ = [&](size_t n) { u16* p = Wu + ou; ou += n; return p; };
    u16* in_spb    = au_((size_t)2048 * 512);
    u16* in_sub    = au_((size_t)512 * 512);
    u16* spb       = au_((size_t)2048 * 512);
    u16* sub       = au_((size_t)512 * 512);
    u16* ge2eb     = au_((size_t)4096 * 512);
    u16* gn2eb     = au_((size_t)4096 * 512);
    u16* qkv_sa    = au_((size_t)2048 * 1536);
    u16* qkv_san   = au_((size_t)512 * 1536);
    u16* qkv_n2n   = au_((size_t)512 * 1536);
    u16* qe2eb     = au_((size_t)2048 * 512);
    u16* qn2eb     = au_((size_t)512 * 512);
    u16* kv1       = au_((size_t)4096 * 1024);
    u16* kv2       = au_((size_t)4096 * 1024);
    u16* attb_sa   = au_((size_t)2048 * 512);
    u16* attb_san  = au_((size_t)512 * 512);
    u16* attb_e2e  = au_((size_t)2048 * 512);
    u16* attb_n2e  = au_((size_t)512 * 512);
    u16* attb_n2n  = au_((size_t)512 * 512);
    u16* tmp1b     = au_((size_t)2048 * 512);
    u16* tmp1bu    = au_((size_t)512 * 512);
    u16* ffnb      = au_((size_t)2048 * 2048);
    u16* ffnbu     = au_((size_t)512 * 2048);
    u16* vtb_sa    = au_((size_t)16 * 64 * 1024);
    u16* vtb_san   = au_((size_t)16 * 64 * 256);
    u16* vtb_e2e   = au_((size_t)16 * 64 * 2048);
    u16* vtb_n2e   = au_((size_t)16 * 64 * 2048);
    u16* vtb_n2n   = au_((size_t)16 * 64 * 256);
    u16* probs_e2e = au_((size_t)16 * 1024 * 2048);
    u16* probs_n2e = au_((size_t)16 * 256 * 2048);
    u16* probs_n2n = au_((size_t)16 * 256 * 256);
    u16* wb[14];
    const int wsz[14] = {786432, 262144, 786432, 262144, 786432, 262144, 786432,
                         262144, 786432, 262144, 1048576, 1048576, 1048576, 1048576};
    for (int i = 0; i < 14; ++i) wb[i] = au_((size_t)wsz[i]);
    int* inv = (int*)(Wu + ou);

    float* out_uu = (float*)d_out;
    float* out_up = out_uu + 262144;
    float* out_w1 = out_up + 1048576;
    float* out_w2 = out_w1 + 4194304;
    float* out_w3 = out_w2 + 4194304;
    float* out_w4 = out_w3 + 1048576;

    const dim3 blk(256);

    CvtDesc cd;
    const float* wsrc[14] = {Wi_sa, Wo_sa, Wi_san, Wo_san, Wi_e2e, Wo_e2e, Wi_n2e,
                             Wo_n2e, Wi_n2n, Wo_n2n, W1, W2, W1u, W2u};
    for (int i = 0; i < 14; ++i) { cd.src[i] = wsrc[i]; cd.dst[i] = wb[i]; cd.n4[i] = wsz[i] / 4; }
    cd.src[14] = in_sp; cd.dst[14] = in_spb; cd.n4[14] = 1048576 / 4;
    cd.src[15] = in_su; cd.dst[15] = in_sub; cd.n4[15] = 262144 / 4;
    cvt_multi<<<dim3(1024, 16), blk, 0, stream>>>(cd);

    init_inv<<<16, blk, 0, stream>>>(inv);
    scatter_inv<<<4, blk, 0, stream>>>(inv, ind_pair, 1024);

    // grouped-GEMM batch builder (tile chosen per batch at flush)
    GGDesc gd{};
    int ng = 0, tot = 0;
    auto gadd = [&](int tile, const u16* A, int lda, const u16* B, int ldb,
                    float* Cf, u16* Ch, int ldc,
                    const float* bias, const float* r1,
                    float scale, int relu, int M, int N, int K) {
        gd.A[ng] = A; gd.B[ng] = B; gd.Cf[ng] = Cf; gd.Ch[ng] = Ch;
        gd.bias[ng] = bias; gd.res1[ng] = r1;
        gd.lda[ng] = lda; gd.ldb[ng] = ldb; gd.ldc[ng] = ldc;
        gd.K[ng] = K; gd.relu[ng] = relu; gd.nt[ng] = N / tile;
        gd.off[ng] = tot; gd.scale[ng] = scale;
        tot += (M / tile) * (N / tile); ++ng;
    };
    auto gflush = [&](int tile) {
        gd.ngroups = ng;
        if (tile == 128) gg_gemm<128, 128><<<tot, blk, 0, stream>>>(gd);
        else             gg_gemm<64, 64><<<tot, blk, 0, stream>>>(gd);
        ng = 0; tot = 0;
    };

    // grouped vtrans / flash / merge / avg builders
    VTDesc vd{}; int vng = 0, vtot = 0;
    auto vadd = [&](const u16* V, int ldv, u16* vT, int S) {
        vd.V[vng] = V; vd.vT[vng] = vT; vd.ldv[vng] = ldv; vd.S[vng] = S;
        vd.off[vng] = vtot; vtot += (S / 64) * 16; ++vng;
    };
    auto vflush = [&]() {
        vd.ng = vng;
        vtrans_g<<<vtot, blk, 0, stream>>>(vd);
        vng = 0; vtot = 0;
    };

    FADesc fd{}; int fng = 0, ftot = 0;
    auto fadd = [&](const u16* Q, int ldq, const u16* Kp, int ldk, const u16* vT,
                    u16* scores, float* Of, float2* pml, int L, int S, int nch) {
        fd.Q[fng] = Q; fd.Kp[fng] = Kp; fd.vT[fng] = vT; fd.scores[fng] = scores;
        fd.Of[fng] = Of; fd.pml[fng] = pml;
        fd.ldq[fng] = ldq; fd.ldk[fng] = ldk; fd.L[fng] = L; fd.S[fng] = S;
        fd.CS[fng] = S / nch; fd.off[fng] = ftot;
        ftot += (L / 64) * 16 * nch; ++fng;
    };
    auto fflush = [&](bool needW) {
        fd.ng = fng;
        if (needW) attn_flash64g<true><<<ftot, blk, 0, stream>>>(fd);
        else       attn_flash64g<false><<<ftot, blk, 0, stream>>>(fd);
        fng = 0; ftot = 0;
    };

    MGDesc md{}; int mng = 0, mtot = 0;
    auto madd = [&](const float* Of, const float2* pml, u16* att, float2* stats,
                    int L, int nch) {
        md.Of[mng] = Of; md.pml[mng] = pml; md.att[mng] = att; md.stats[mng] = stats;
        md.L[mng] = L; md.nch[mng] = nch; md.off[mng] = mtot;
        mtot += 16 * L / 4; ++mng;
    };
    auto mflush = [&]() {
        md.ng = mng;
        attn_merge_g<<<mtot, blk, 0, stream>>>(md);
        mng = 0; mtot = 0;
    };

    AVDesc ad{}; int ang = 0, atot = 0;
    auto aadd = [&](const u16* P, const float2* st, float* o1, float* o2, int L, int S) {
        ad.P[ang] = P; ad.st[ang] = st; ad.out1[ang] = o1; ad.out2[ang] = o2;
        ad.L[ang] = L; ad.S[ang] = S; ad.off[ang] = atot;
        atot += 2 * L; ++ang;
    };
    auto aflush = [&]() {
        ad.ng = ang;
        avg_softmax_g<<<atot, blk, 0, stream>>>(ad);
        ang = 0; atot = 0;
    };

    auto lnpair = [&](const float* Xa, const float* X2a, const float* ga, const float* ba,
                      float* Yfa, u16* Yba, int Ra,
                      const float* Xb, const float* X2b, const float* gb2, const float* bb2,
                      float* Yfb, u16* Ybb, int Rb) {
        LN2Desc ld;
        ld.X[0] = Xa; ld.X2[0] = X2a; ld.gam[0] = ga; ld.bet[0] = ba; ld.Yf[0] = Yfa; ld.Yb[0] = Yba;
        ld.X[1] = Xb; ld.X2[1] = X2b; ld.gam[1] = gb2; ld.bet[1] = bb2; ld.Yf[1] = Yfb; ld.Yb[1] = Ybb;
        ld.R0 = Ra;
        ln512_g<<<Ra + Rb, blk, 0, stream>>>(ld);
    };

    // ===== G1 (128-tile): both self-attention QKV projections =====
    gadd(128, in_spb, 512, wb[0], 512, nullptr, qkv_sa, 1536, bi_sa, nullptr, 1.f, 0, 2048, 1536, 512);
    gadd(128, in_sub, 512, wb[2], 512, nullptr, qkv_san, 1536, bi_san, nullptr, 1.f, 0, 512, 1536, 512);
    gflush(128);

    // ===== batch A: both self-attentions =====
    vadd(qkv_sa + 1024, 1536, vtb_sa, 1024);
    vadd(qkv_san + 1024, 1536, vtb_san, 256);
    vflush();
    fadd(qkv_sa, 1536, qkv_sa + 512, 1536, vtb_sa, nullptr, ofp_sa, pml_sa, 1024, 1024, 4);
    fadd(qkv_san, 1536, qkv_san + 512, 1536, vtb_san, nullptr, ofp_san, pml_san, 256, 256, 4);
    fflush(false);
    madd(ofp_sa, pml_sa, attb_sa, nullptr, 1024, 4);
    madd(ofp_san, pml_san, attb_san, nullptr, 256, 4);
    mflush();

    // ===== G2 (64-tile): both self-attention output projections =====
    gadd(64, attb_sa, 512, wb[1], 512, tmp0f, nullptr, 512, bo_sa, in_sp, 1.f, 0, 2048, 512, 512);
    gadd(64, attb_san, 512, wb[3], 512, tmp0fu, nullptr, 512, bo_san, in_su, 1.f, 0, 512, 512, 512);
    gflush(64);
    lnpair(tmp0f, nullptr, g1, be1, spf, spb, 2048,
           tmp0fu, nullptr, g1u, be1u, suf, sub, 512);

    // ===== gathers (one launch) =====
    gather_rows_bf2<<<dim3(2048, 2), blk, 0, stream>>>(
        ge2eb, gn2eb, spf, in_ep, ind_e2e, ind_n2e, inv, 524288);

    // ===== G3a (128-tile): both KV projections =====
    gadd(128, ge2eb, 512, wb[4] + 262144, 512, nullptr, kv1, 1024, bi_e2e + 512, nullptr, 1.f, 0, 4096, 1024, 512);
    gadd(128, gn2eb, 512, wb[6] + 262144, 512, nullptr, kv2, 1024, bi_n2e + 512, nullptr, 1.f, 0, 4096, 1024, 512);
    gflush(128);
    // ===== G3b (64-tile): the three Q/QKV projections =====
    gadd(64, spb, 512, wb[4], 512, nullptr, qe2eb, 512, bi_e2e, nullptr, 1.f, 0, 2048, 512, 512);
    gadd(64, sub, 512, wb[6], 512, nullptr, qn2eb, 512, bi_n2e, nullptr, 1.f, 0, 512, 512, 512);
    gadd(64, sub, 512, wb[8], 512, nullptr, qkv_n2n, 1536, bi_n2n, nullptr, 1.f, 0, 512, 1536, 512);
    gflush(64);

    // ===== batch B: all three weight-producing attentions =====
    vadd(kv1 + 512, 1024, vtb_e2e, 2048);
    vadd(kv2 + 512, 1024, vtb_n2e, 2048);
    vadd(qkv_n2n + 1024, 1536, vtb_n2n, 256);
    vflush();
    fadd(qe2eb, 512, kv1, 1024, vtb_e2e, probs_e2e, ofp_e2e, pml_e2e, 1024, 2048, 4);
    fadd(qn2eb, 512, kv2, 1024, vtb_n2e, probs_n2e, ofp_n2e, pml_n2e, 256, 2048, 8);
    fadd(qkv_n2n, 1536, qkv_n2n + 512, 1536, vtb_n2n, probs_n2n, ofp_n2n, pml_n2n, 256, 256, 4);
    fflush(true);
    madd(ofp_e2e, pml_e2e, attb_e2e, st_e2e, 1024, 4);
    madd(ofp_n2e, pml_n2e, attb_n2e, st_n2e, 256, 8);
    madd(ofp_n2n, pml_n2n, attb_n2n, st_n2n, 256, 4);
    mflush();
    aadd(probs_e2e, st_e2e, out_w1, out_w2, 1024, 2048);
    aadd(probs_n2e, st_n2e, out_w3, nullptr, 256, 2048);
    aadd(probs_n2n, st_n2n, out_w4, nullptr, 256, 256);
    aflush();

    // ===== G4 (64-tile): all three output projections =====
    gadd(64, attb_e2e, 512, wb[5], 512, tmp0f, nullptr, 512, bo_e2e, spf, 2.f, 0, 2048, 512, 512);
    gadd(64, attb_n2e, 512, wb[7], 512, upn2ef, nullptr, 512, bo_n2e, nullptr, 1.f, 0, 512, 512, 512);
    gadd(64, attb_n2n, 512, wb[9], 512, upn2nf, nullptr, 512, bo_n2n, suf, 1.f, 0, 512, 512, 512);
    gflush(64);
    lnpair(tmp0f, nullptr, g2, be2, tmp1f, tmp1b, 2048,
           upn2nf, upn2ef, g2, be2, tmp1fu, tmp1bu, 512);

    // ===== G5 (128-tile): both FFN up-projections (relu) =====
    gadd(128, tmp1b, 512, wb[10], 512, nullptr, ffnb, 2048, b1f, nullptr, 1.f, 1, 2048, 2048, 512);
    gadd(128, tmp1bu, 512, wb[12], 512, nullptr, ffnbu, 2048, b1fu, nullptr, 1.f, 1, 512, 2048, 512);
    gflush(128);

    // ===== G6 (64-tile): both FFN down-projections (+residual) =====
    gadd(64, ffnb, 2048, wb[11], 2048, tmp0f, nullptr, 512, b2f, tmp1f, 1.f, 0, 2048, 512, 2048);
    gadd(64, ffnbu, 2048, wb[13], 2048, tmp0fu, nullptr, 512, b2fu, tmp1fu, 1.f, 0, 512, 512, 2048);
    gflush(64);

    lnpair(tmp0f, nullptr, g3, be3, out_up, nullptr, 2048,
           tmp0fu, nullptr, g3, be3, out_uu, nullptr, 512);
}

// Round 12
// 452.292 us; speedup vs baseline: 1.0215x; 1.0215x over previous
//
#include <hip/hip_runtime.h>
#include <cstddef>

#define LN_EPS 1e-5f

typedef unsigned short u16;
typedef short short8 __attribute__((ext_vector_type(8)));
typedef float f32x4 __attribute__((ext_vector_type(4)));

__device__ __forceinline__ u16 f2bf(float f) {
    unsigned int u = __float_as_uint(f);
    u = (u + 0x7FFFu + ((u >> 16) & 1u)) >> 16;
    return (u16)u;
}
__device__ __forceinline__ float bf2f(u16 h) {
    return __uint_as_float((unsigned int)h << 16);
}
// packed RNE f32x2 -> bf16x2 (lo = a, hi = b)
__device__ __forceinline__ unsigned int pk_bf16(float a, float b) {
    unsigned int r;
    asm("v_cvt_pk_bf16_f32 %0, %1, %2" : "=v"(r) : "v"(a), "v"(b));
    return r;
}

// ---------------------------------------------------------------------------
// Multi-tensor fp32 -> bf16 convert (weights + inputs), one launch.
// ---------------------------------------------------------------------------
struct CvtDesc {
    const float* src[16];
    u16* dst[16];
    int n4[16];
};
__global__ __launch_bounds__(256) void cvt_multi(CvtDesc d) {
    const int t = blockIdx.x * 256 + threadIdx.x;
    const int i = blockIdx.y;
    if (t >= d.n4[i]) return;
    const float4 v = ((const float4*)d.src[i])[t];
    ushort4 o;
    o.x = f2bf(v.x); o.y = f2bf(v.y); o.z = f2bf(v.z); o.w = f2bf(v.w);
    ((ushort4*)d.dst[i])[t] = o;
}

// ---------------------------------------------------------------------------
// GROUPED bf16 MFMA NT GEMM, 64x64 tile / 4 waves / BK=64 (round-10 verified
// config: with descriptor-grouping, small tiles + big uniform grids beat fat
// tiles + sparse grids — round-11 lesson). Group via prefix-offset scan.
// C = scale*(A@B^T + bias) + res1 (+relu). Outputs fp32 and/or bf16.
// ---------------------------------------------------------------------------
struct GGDesc {
    const u16* A[6]; const u16* B[6];
    float* Cf[6]; u16* Ch[6];
    const float* bias[6]; const float* res1[6];
    int lda[6], ldb[6], ldc[6], K[6], relu[6], nt[6], off[6];
    float scale[6];
    int ngroups;
};
__global__ __launch_bounds__(256) void gg_gemm(GGDesc d) {
    __shared__ u16 As[64 * 72];
    __shared__ u16 Bs[64 * 72];

    int g = 0;
    const int bid = blockIdx.x;
    while (g + 1 < d.ngroups && bid >= d.off[g + 1]) ++g;
    const int local = bid - d.off[g];
    const int m0 = (local / d.nt[g]) * 64;
    const int n0 = (local % d.nt[g]) * 64;

    const u16* __restrict__ A = d.A[g];
    const u16* __restrict__ B = d.B[g];
    const int lda = d.lda[g], ldb = d.ldb[g], ldc = d.ldc[g];
    const int K = d.K[g], relu = d.relu[g];
    const float scale = d.scale[g];

    const int tid = threadIdx.x;
    const int wave = tid >> 6, lane = tid & 63;
    const int wm = wave >> 1, wn = wave & 1;

    f32x4 acc[2][2];
#pragma unroll
    for (int mf = 0; mf < 2; ++mf)
#pragma unroll
        for (int nf = 0; nf < 2; ++nf) acc[mf][nf] = (f32x4){0.f, 0.f, 0.f, 0.f};

    const int ar = tid >> 3, ac = (tid & 7) * 8;
    const int ml = lane & 15, kq = lane >> 4;

    short8 aN[2], bN[2];
#pragma unroll
    for (int c = 0; c < 2; ++c)
        aN[c] = *(const short8*)&A[(size_t)(m0 + ar + c * 32) * lda + ac];
#pragma unroll
    for (int c = 0; c < 2; ++c)
        bN[c] = *(const short8*)&B[(size_t)(n0 + ar + c * 32) * ldb + ac];

    for (int k0 = 0; k0 < K; k0 += 64) {
        short8 aS[2], bS[2];
#pragma unroll
        for (int c = 0; c < 2; ++c) { aS[c] = aN[c]; bS[c] = bN[c]; }
        if (k0 + 64 < K) {
#pragma unroll
            for (int c = 0; c < 2; ++c)
                aN[c] = *(const short8*)&A[(size_t)(m0 + ar + c * 32) * lda + k0 + 64 + ac];
#pragma unroll
            for (int c = 0; c < 2; ++c)
                bN[c] = *(const short8*)&B[(size_t)(n0 + ar + c * 32) * ldb + k0 + 64 + ac];
        }
        __syncthreads();
#pragma unroll
        for (int c = 0; c < 2; ++c) *(short8*)&As[(ar + c * 32) * 72 + ac] = aS[c];
#pragma unroll
        for (int c = 0; c < 2; ++c) *(short8*)&Bs[(ar + c * 32) * 72 + ac] = bS[c];
        __syncthreads();

        short8 af0[2], af1[2], bf0[2], bf1[2];
#pragma unroll
        for (int mf = 0; mf < 2; ++mf) {
            const int base = (wm * 32 + mf * 16 + ml) * 72 + kq * 8;
            af0[mf] = *(const short8*)&As[base];
            af1[mf] = *(const short8*)&As[base + 32];
        }
#pragma unroll
        for (int nf = 0; nf < 2; ++nf) {
            const int base = (wn * 32 + nf * 16 + ml) * 72 + kq * 8;
            bf0[nf] = *(const short8*)&Bs[base];
            bf1[nf] = *(const short8*)&Bs[base + 32];
        }
#pragma unroll
        for (int mf = 0; mf < 2; ++mf)
#pragma unroll
            for (int nf = 0; nf < 2; ++nf) {
                acc[mf][nf] = __builtin_amdgcn_mfma_f32_16x16x32_bf16(
                    af0[mf], bf0[nf], acc[mf][nf], 0, 0, 0);
                acc[mf][nf] = __builtin_amdgcn_mfma_f32_16x16x32_bf16(
                    af1[mf], bf1[nf], acc[mf][nf], 0, 0, 0);
            }
    }

    float* __restrict__ Cf = d.Cf[g];
    u16* __restrict__ Ch = d.Ch[g];
    const float* __restrict__ bias = d.bias[g];
    const float* __restrict__ res1 = d.res1[g];
    const int rq = lane >> 4;
#pragma unroll
    for (int mf = 0; mf < 2; ++mf)
#pragma unroll
        for (int nf = 0; nf < 2; ++nf) {
            const int col = n0 + wn * 32 + nf * 16 + ml;
            const float bv = bias ? bias[col] : 0.f;
#pragma unroll
            for (int r = 0; r < 4; ++r) {
                const int row = m0 + wm * 32 + mf * 16 + rq * 4 + r;
                float v = scale * (acc[mf][nf][r] + bv);
                const size_t idx = (size_t)row * ldc + col;
                if (res1) v += res1[idx];
                if (relu) v = fmaxf(v, 0.f);
                if (Cf) Cf[idx] = v;
                if (Ch) Ch[idx] = f2bf(v);
            }
        }
}

// ---------------------------------------------------------------------------
// GROUPED V transpose (within-64 permuted layout; see attn_flash64g).
// ---------------------------------------------------------------------------
struct VTDesc {
    const u16* V[3]; u16* vT[3]; int ldv[3], S[3], off[3]; int ng;
};
__global__ __launch_bounds__(256) void vtrans_g(VTDesc d) {
    __shared__ u16 Vs[64 * 72];
    int g = 0;
    const int bid = blockIdx.x;
    while (g + 1 < d.ng && bid >= d.off[g + 1]) ++g;
    const int local = bid - d.off[g];
    const int S = d.S[g], ldv = d.ldv[g];
    const int nS = S >> 6;
    const int s0 = (local % nS) * 64;
    const int bh = local / nS, b = bh & 1, h = bh >> 1;
    const u16* __restrict__ V = d.V[g];
    u16* __restrict__ vT = d.vT[g];
    const int tid = threadIdx.x;

#pragma unroll
    for (int c = 0; c < 2; ++c) {
        const int idx = tid + c * 256;
        const int sr = idx >> 3, dc = (idx & 7) * 8;
        *(short8*)&Vs[sr * 72 + dc] =
            *(const short8*)&V[(size_t)((s0 + sr) * 2 + b) * ldv + h * 64 + dc];
    }
    __syncthreads();
#pragma unroll
    for (int c = 0; c < 2; ++c) {
        const int idx = tid + c * 256;
        const int dr = idx >> 3, sc = (idx & 7) * 8;
        short8 o;
#pragma unroll
        for (int j = 0; j < 8; ++j) {
            const int p = sc + j;
            o[j] = (short)Vs[((p >> 2) + 16 * (p & 3)) * 72 + dr];
        }
        *(short8*)&vT[(size_t)bh * 64 * S + (size_t)dr * S + s0 + sc] = o;
    }
}

// ---------------------------------------------------------------------------
// GROUPED split-S flash attention (round-8 verified body, descriptor-batched;
// up to 3 independent attentions per launch). Separate merge kernel (stream
// boundary provides cross-block ordering — NO device fences, round-7 lesson).
// ---------------------------------------------------------------------------
struct FADesc {
    const u16* Q[3]; const u16* Kp[3]; const u16* vT[3]; u16* scores[3];
    float* Of[3]; float2* pml[3];
    int ldq[3], ldk[3], L[3], S[3], CS[3], off[3];
    int ng;
};
template<bool NEED_W>
__global__ __launch_bounds__(256) void attn_flash64g(FADesc d) {
    __shared__ u16 Ks[64 * 72];
    __shared__ u16 Vt[64 * 72];
    __shared__ u16 St[4][16 * 72];

    int g = 0;
    const int bid = blockIdx.x;
    while (g + 1 < d.ng && bid >= d.off[g + 1]) ++g;
    int local = bid - d.off[g];
    const int L = d.L[g], S = d.S[g], CS = d.CS[g];
    const int ldq = d.ldq[g], ldk = d.ldk[g];
    const int nx = L >> 6;
    const int bx = local % nx; local /= nx;
    const int bz = local & 15;
    const int chunk = local >> 4;

    const u16* __restrict__ Q = d.Q[g];
    const u16* __restrict__ Kp = d.Kp[g];
    const u16* __restrict__ vT = d.vT[g];
    float* __restrict__ Of = d.Of[g];
    float2* __restrict__ pml = d.pml[g];

    const int tid = threadIdx.x;
    const int wave = tid >> 6, lane = tid & 63;
    const int ml = lane & 15, rq = lane >> 4;
    const int i0 = bx * 64;
    const int bb = bz & 1, hh = bz >> 1;
    const int cs0 = chunk * CS;
    u16* Sb = NEED_W ? d.scores[g] + (size_t)bz * L * S + (size_t)i0 * S : nullptr;
    const u16* Vbase = vT + (size_t)bz * 64 * S;

    const int qrow = i0 + wave * 16 + ml;
    const short8 qf0 = *(const short8*)&Q[(size_t)(qrow * 2 + bb) * ldq + hh * 64 + rq * 8];
    const short8 qf1 = *(const short8*)&Q[(size_t)(qrow * 2 + bb) * ldq + hh * 64 + 32 + rq * 8];

    float mrun[4], lrun[4];
    f32x4 acc[4];
#pragma unroll
    for (int r = 0; r < 4; ++r) {
        mrun[r] = -1e30f; lrun[r] = 0.f;
        acc[r] = (f32x4){0.f, 0.f, 0.f, 0.f};
    }

    const int sr0 = tid >> 3, dc0 = (tid & 7) * 8;
    const int sr1 = (tid + 256) >> 3, dc1 = ((tid + 256) & 7) * 8;

    short8 kr0 = *(const short8*)&Kp[(size_t)((cs0 + sr0) * 2 + bb) * ldk + hh * 64 + dc0];
    short8 kr1 = *(const short8*)&Kp[(size_t)((cs0 + sr1) * 2 + bb) * ldk + hh * 64 + dc1];
    short8 vr0 = *(const short8*)&Vbase[(size_t)sr0 * S + cs0 + dc0];
    short8 vr1 = *(const short8*)&Vbase[(size_t)sr1 * S + cs0 + dc1];

    u16* Sw = St[wave];

    for (int k0 = cs0; k0 < cs0 + CS; k0 += 64) {
        __syncthreads();
        *(short8*)&Ks[sr0 * 72 + dc0] = kr0;
        *(short8*)&Ks[sr1 * 72 + dc1] = kr1;
        *(short8*)&Vt[sr0 * 72 + dc0] = vr0;
        *(short8*)&Vt[sr1 * 72 + dc1] = vr1;
        if (k0 + 64 < cs0 + CS) {
            const int kn = k0 + 64;
            kr0 = *(const short8*)&Kp[(size_t)((kn + sr0) * 2 + bb) * ldk + hh * 64 + dc0];
            kr1 = *(const short8*)&Kp[(size_t)((kn + sr1) * 2 + bb) * ldk + hh * 64 + dc1];
            vr0 = *(const short8*)&Vbase[(size_t)sr0 * S + kn + dc0];
            vr1 = *(const short8*)&Vbase[(size_t)sr1 * S + kn + dc1];
        }
        __syncthreads();

        f32x4 sc[4];
#pragma unroll
        for (int nf = 0; nf < 4; ++nf) {
            const short8 kf0 = *(const short8*)&Ks[(nf * 16 + ml) * 72 + rq * 8];
            const short8 kf1 = *(const short8*)&Ks[(nf * 16 + ml) * 72 + 32 + rq * 8];
            f32x4 s = (f32x4){0.f, 0.f, 0.f, 0.f};
            s = __builtin_amdgcn_mfma_f32_16x16x32_bf16(qf0, kf0, s, 0, 0, 0);
            s = __builtin_amdgcn_mfma_f32_16x16x32_bf16(qf1, kf1, s, 0, 0, 0);
#pragma unroll
            for (int r = 0; r < 4; ++r) s[r] *= 0.125f;
            sc[nf] = s;
        }

        if (NEED_W) {
#pragma unroll
            for (int r = 0; r < 4; ++r) {
                const unsigned int pk0 = pk_bf16(sc[0][r], sc[1][r]);
                const unsigned int pk1 = pk_bf16(sc[2][r], sc[3][r]);
                *(uint2*)&Sb[(size_t)(wave * 16 + rq * 4 + r) * S + k0 + ml * 4] =
                    make_uint2(pk0, pk1);
            }
        }

        float tm[4];
#pragma unroll
        for (int r = 0; r < 4; ++r)
            tm[r] = fmaxf(fmaxf(sc[0][r], sc[1][r]), fmaxf(sc[2][r], sc[3][r]));
#pragma unroll
        for (int mk = 1; mk < 16; mk <<= 1)
#pragma unroll
            for (int r = 0; r < 4; ++r)
                tm[r] = fmaxf(tm[r], __shfl_xor(tm[r], mk));

        float alpha[4], mn[4];
#pragma unroll
        for (int r = 0; r < 4; ++r) {
            mn[r] = fmaxf(mrun[r], tm[r]);
            alpha[r] = __expf(mrun[r] - mn[r]);
            mrun[r] = mn[r];
        }

        float rs[4];
#pragma unroll
        for (int r = 0; r < 4; ++r) {
            const float p0 = __expf(sc[0][r] - mn[r]);
            const float p1 = __expf(sc[1][r] - mn[r]);
            const float p2 = __expf(sc[2][r] - mn[r]);
            const float p3 = __expf(sc[3][r] - mn[r]);
            rs[r] = (p0 + p1) + (p2 + p3);
            const unsigned int pk0 = pk_bf16(p0, p1);
            const unsigned int pk1 = pk_bf16(p2, p3);
            *(uint2*)&Sw[(rq * 4 + r) * 72 + ml * 4] = make_uint2(pk0, pk1);
        }
#pragma unroll
        for (int mk = 1; mk < 16; mk <<= 1)
#pragma unroll
            for (int r = 0; r < 4; ++r)
                rs[r] += __shfl_xor(rs[r], mk);
#pragma unroll
        for (int r = 0; r < 4; ++r)
            lrun[r] = lrun[r] * alpha[r] + rs[r];

#pragma unroll
        for (int df = 0; df < 4; ++df)
#pragma unroll
            for (int r = 0; r < 4; ++r)
                acc[df][r] *= alpha[r];
#pragma unroll
        for (int kc = 0; kc < 2; ++kc) {
            const short8 afr = *(const short8*)&Sw[ml * 72 + kc * 32 + rq * 8];
#pragma unroll
            for (int df = 0; df < 4; ++df) {
                const short8 bfr = *(const short8*)&Vt[(df * 16 + ml) * 72 + kc * 32 + rq * 8];
                acc[df] = __builtin_amdgcn_mfma_f32_16x16x32_bf16(afr, bfr, acc[df], 0, 0, 0);
            }
        }
    }

#pragma unroll
    for (int df = 0; df < 4; ++df)
#pragma unroll
        for (int r = 0; r < 4; ++r) {
            const int i = i0 + wave * 16 + rq * 4 + r;
            Of[((size_t)(chunk * 16 + bz) * L + i) * 64 + df * 16 + ml] = acc[df][r];
        }
    if (ml == 0) {
#pragma unroll
        for (int r = 0; r < 4; ++r)
            pml[(size_t)chunk * 16 * L + (size_t)bz * L + i0 + wave * 16 + rq * 4 + r] =
                make_float2(mrun[r], lrun[r]);
    }
}

// ---------------------------------------------------------------------------
// GROUPED merge of split-S partials. stats written iff stats[g] != null.
// ---------------------------------------------------------------------------
struct MGDesc {
    const float* Of[3]; const float2* pml[3]; u16* att[3]; float2* stats[3];
    int L[3], nch[3], off[3]; int ng;
};
__global__ __launch_bounds__(256) void attn_merge_g(MGDesc d) {
    int gg = 0;
    const int bid = blockIdx.x;
    while (gg + 1 < d.ng && bid >= d.off[gg + 1]) ++gg;
    const int local = bid - d.off[gg];
    const int L = d.L[gg], nchunks = d.nch[gg];
    const float* __restrict__ Of = d.Of[gg];
    const float2* __restrict__ pml = d.pml[gg];

    const int tid = threadIdx.x;
    const int grow = local * 4 + (tid >> 6);
    const int dcol = tid & 63;
    const int bz = grow / L, i = grow - bz * L;
    const int bb = bz & 1, hh = bz >> 1;

    float M = -1e30f;
    for (int c = 0; c < nchunks; ++c)
        M = fmaxf(M, pml[(size_t)c * 16 * L + grow].x);
    float T = 0.f, O = 0.f;
    for (int c = 0; c < nchunks; ++c) {
        const float2 w2 = pml[(size_t)c * 16 * L + grow];
        const float w = __expf(w2.x - M);
        T += w2.y * w;
        O += w * Of[((size_t)(c * 16 + bz) * L + i) * 64 + dcol];
    }
    const float invT = 1.0f / T;
    d.att[gg][((size_t)i * 2 + bb) * 512 + hh * 64 + dcol] = f2bf(O * invT);
    if (d.stats[gg] && dcol == 0)
        d.stats[gg][(size_t)bz * L + i] = make_float2(M, invT);
}

// ---------------------------------------------------------------------------
// GROUPED head-average + second softmax. probs permuted-within-64; un-permute
// via LDS, coalesced float4 final writes.
// ---------------------------------------------------------------------------
struct AVDesc {
    const u16* P[3]; const float2* st[3]; float* out1[3]; float* out2[3];
    int L[3], S[3], off[3]; int ng;
};
__global__ __launch_bounds__(256) void avg_softmax_g(AVDesc d) {
    __shared__ float red[256];
    __shared__ float stage[2048];
    int g = 0;
    const int bid = blockIdx.x;
    while (g + 1 < d.ng && bid >= d.off[g + 1]) ++g;
    const int local = bid - d.off[g];
    const int L = d.L[g], S = d.S[g];
    const int b = local / L, i = local % L;
    const u16* __restrict__ P = d.P[g];
    const float2* __restrict__ st = d.st[g];
    const size_t LS = (size_t)L * S;
    const int tid = threadIdx.x;
    const bool act = tid * 8 < S;

    float acc[8] = {};
    if (act) {
#pragma unroll
        for (int h = 0; h < 8; ++h) {
            const int bh = h * 2 + b;
            const float2 s = st[(size_t)bh * L + i];
            const short8 r8 = *(const short8*)&P[(size_t)bh * LS + (size_t)i * S + tid * 8];
#pragma unroll
            for (int j = 0; j < 8; ++j)
                acc[j] += __expf(bf2f((u16)r8[j]) - s.x) * s.y;
        }
#pragma unroll
        for (int j = 0; j < 8; ++j) acc[j] *= 0.125f;
    }
    float lmax = -1e30f;
    if (act) {
#pragma unroll
        for (int j = 0; j < 8; ++j) lmax = fmaxf(lmax, acc[j]);
    }
    red[tid] = lmax; __syncthreads();
    for (int s = 128; s; s >>= 1) {
        if (tid < s) red[tid] = fmaxf(red[tid], red[tid + s]);
        __syncthreads();
    }
    const float mx = red[0]; __syncthreads();
    float e[8];
    float ls = 0.f;
    if (act) {
#pragma unroll
        for (int j = 0; j < 8; ++j) { e[j] = __expf(acc[j] - mx); ls += e[j]; }
    }
    red[tid] = ls; __syncthreads();
    for (int s = 128; s; s >>= 1) {
        if (tid < s) red[tid] += red[tid + s];
        __syncthreads();
    }
    const float inv = 1.0f / red[0];
    if (act) {
        const int g64 = (tid >> 3) * 64;
        const int t2 = (tid & 7) * 2;
#pragma unroll
        for (int j = 0; j < 8; ++j) {
            const int c = t2 + (j >> 2) + 16 * (j & 3);
            stage[g64 + c] = e[j] * inv;
        }
    }
    __syncthreads();
    float* out1 = d.out1[g];
    float* out2 = d.out2[g];
    const size_t base = (size_t)local * S;
    for (int idx = tid * 4; idx < S; idx += 1024) {
        const float4 v = *(const float4*)&stage[idx];
        *(float4*)&out1[base + idx] = v;
        if (out2) *(float4*)&out2[base + idx] = v;
    }
}

// ---------------------------------------------------------------------------
// LayerNorm over rows of 512 of (X + optional X2); PAIRED: two groups per
// launch (blockIdx < R0 -> group 0).
// ---------------------------------------------------------------------------
struct LN2Desc {
    const float* X[2]; const float* X2[2];
    const float* gam[2]; const float* bet[2];
    float* Yf[2]; u16* Yb[2]; int R0;
};
__global__ __launch_bounds__(256) void ln512_g(LN2Desc d) {
    __shared__ float red[256];
    const int gi = (blockIdx.x < (unsigned)d.R0) ? 0 : 1;
    const int r = gi ? (blockIdx.x - d.R0) : blockIdx.x;
    const int tid = threadIdx.x;
    const float* xr = d.X[gi] + (size_t)r * 512;
    float x0 = xr[tid], x1 = xr[tid + 256];
    if (d.X2[gi]) {
        const float* x2r = d.X2[gi] + (size_t)r * 512;
        x0 += x2r[tid]; x1 += x2r[tid + 256];
    }
    red[tid] = x0 + x1; __syncthreads();
    for (int st = 128; st; st >>= 1) {
        if (tid < st) red[tid] += red[tid + st];
        __syncthreads();
    }
    const float mean = red[0] * (1.0f / 512.0f); __syncthreads();
    const float d0 = x0 - mean, d1 = x1 - mean;
    red[tid] = d0 * d0 + d1 * d1; __syncthreads();
    for (int st = 128; st; st >>= 1) {
        if (tid < st) red[tid] += red[tid + st];
        __syncthreads();
    }
    const float rstd = rsqrtf(red[0] * (1.0f / 512.0f) + LN_EPS);
    const float y0 = d0 * rstd * d.gam[gi][tid] + d.bet[gi][tid];
    const float y1 = d1 * rstd * d.gam[gi][tid + 256] + d.bet[gi][tid + 256];
    float* yr = d.Yf[gi] + (size_t)r * 512;
    yr[tid] = y0; yr[tid + 256] = y1;
    if (d.Yb[gi]) {
        u16* yb = d.Yb[gi] + (size_t)r * 512;
        yb[tid] = f2bf(y0); yb[tid + 256] = f2bf(y1);
    }
}

// ---------------------------------------------------------------------------
// pair assembly: inverse map + gathers (both destinations in one launch).
// ---------------------------------------------------------------------------
__global__ void init_inv(int* __restrict__ inv) {
    const int i = blockIdx.x * 256 + threadIdx.x;
    if (i < 4096) inv[i] = -1;
}
__global__ void scatter_inv(int* __restrict__ inv, const int* __restrict__ ind, int n) {
    const int i = blockIdx.x * 256 + threadIdx.x;
    if (i < n) inv[ind[i]] = i;
}
__global__ void gather_rows_bf2(
    u16* __restrict__ dst0, u16* __restrict__ dst1,
    const float* __restrict__ spf, const float* __restrict__ ep,
    const int* __restrict__ ind0, const int* __restrict__ ind1,
    const int* __restrict__ inv, int total4)
{
    const int e = blockIdx.x * 256 + threadIdx.x;
    if (e >= total4) return;
    u16* dst = blockIdx.y ? dst1 : dst0;
    const int* ind = blockIdx.y ? ind1 : ind0;
    const int row = e >> 7, c = e & 127;
    const int j = row >> 1, b = row & 1;
    const int idx = ind[j];
    const int iv = inv[idx];
    const float4* src = (iv >= 0) ? (const float4*)(spf + (size_t)(iv * 2 + b) * 512)
                                  : (const float4*)(ep + (size_t)(idx * 2 + b) * 512);
    const float4 v = src[c];
    ushort4 o; o.x = f2bf(v.x); o.y = f2bf(v.y); o.z = f2bf(v.z); o.w = f2bf(v.w);
    ((ushort4*)dst)[e] = o;
}

// ---------------------------------------------------------------------------
extern "C" void kernel_launch(void* const* d_in, const int* in_sizes, int n_in,
                              void* d_out, int out_size, void* d_ws, size_t ws_size,
                              hipStream_t stream)
{
    (void)in_sizes; (void)n_in; (void)out_size; (void)ws_size;

    const float* in_sp = (const float*)d_in[0];
    const float* in_su = (const float*)d_in[1];
    const float* in_ep = (const float*)d_in[2];
    const int* ind_pair = (const int*)d_in[3];
    const int* ind_e2e  = (const int*)d_in[4];
    const int* ind_n2e  = (const int*)d_in[5];
    const float *Wi_sa  = (const float*)d_in[6],  *bi_sa  = (const float*)d_in[7];
    const float *Wo_sa  = (const float*)d_in[8],  *bo_sa  = (const float*)d_in[9];
    const float *Wi_san = (const float*)d_in[10], *bi_san = (const float*)d_in[11];
    const float *Wo_san = (const float*)d_in[12], *bo_san = (const float*)d_in[13];
    const float *Wi_e2e = (const float*)d_in[14], *bi_e2e = (const float*)d_in[15];
    const float *Wo_e2e = (const float*)d_in[16], *bo_e2e = (const float*)d_in[17];
    const float *Wi_n2e = (const float*)d_in[18], *bi_n2e = (const float*)d_in[19];
    const float *Wo_n2e = (const float*)d_in[20], *bo_n2e = (const float*)d_in[21];
    const float *Wi_n2n = (const float*)d_in[22], *bi_n2n = (const float*)d_in[23];
    const float *Wo_n2n = (const float*)d_in[24], *bo_n2n = (const float*)d_in[25];
    const float *W1  = (const float*)d_in[26], *b1f  = (const float*)d_in[27];
    const float *W2  = (const float*)d_in[28], *b2f  = (const float*)d_in[29];
    const float *W1u = (const float*)d_in[30], *b1fu = (const float*)d_in[31];
    const float *W2u = (const float*)d_in[32], *b2fu = (const float*)d_in[33];
    const float *g1  = (const float*)d_in[34], *g1u = (const float*)d_in[35];
    const float *g2  = (const float*)d_in[36], *g3  = (const float*)d_in[37];
    const float *be1 = (const float*)d_in[38], *be1u = (const float*)d_in[39];
    const float *be2 = (const float*)d_in[40], *be3  = (const float*)d_in[41];

    float* Wf = (float*)d_ws;
    size_t of = 0;
    auto af_ = [&](size_t n) { float* p = Wf + of; of += n; return p; };
    float* spf      = af_((size_t)2048 * 512);
    float* suf      = af_((size_t)512 * 512);
    float* tmp0f    = af_((size_t)2048 * 512);
    float* tmp0fu   = af_((size_t)512 * 512);
    float* upn2ef   = af_((size_t)512 * 512);
    float* upn2nf   = af_((size_t)512 * 512);
    float* tmp1f    = af_((size_t)2048 * 512);
    float* tmp1fu   = af_((size_t)512 * 512);
    float2* st_e2e  = (float2*)af_((size_t)2 * 16 * 1024);
    float2* st_n2e  = (float2*)af_((size_t)2 * 16 * 256);
    float2* st_n2n  = (float2*)af_((size_t)2 * 16 * 256);
    float* ofp_sa   = af_((size_t)4 * 16 * 1024 * 64);
    float* ofp_san  = af_((size_t)4 * 16 * 256 * 64);
    float* ofp_e2e  = af_((size_t)8 * 16 * 1024 * 64);    // e2e now 8 chunks
    float* ofp_n2e  = af_((size_t)8 * 16 * 256 * 64);
    float* ofp_n2n  = af_((size_t)4 * 16 * 256 * 64);
    float2* pml_sa  = (float2*)af_((size_t)2 * 4 * 16 * 1024);
    float2* pml_san = (float2*)af_((size_t)2 * 4 * 16 * 256);
    float2* pml_e2e = (float2*)af_((size_t)2 * 8 * 16 * 1024);
    float2* pml_n2e = (float2*)af_((size_t)2 * 8 * 16 * 256);
    float2* pml_n2n = (float2*)af_((size_t)2 * 4 * 16 * 256);

    u16* Wu = (u16*)(Wf + of);
    size_t ou = 0;
    auto au_ = [&](size_t n) { u16* p = Wu + ou; ou += n; return p; };
    u16* in_spb    = au_((size_t)2048 * 512);
    u16* in_sub    = au_((size_t)512 * 512);
    u16* spb       = au_((size_t)2048 * 512);
    u16* sub       = au_((size_t)512 * 512);
    u16* ge2eb     = au_((size_t)4096 * 512);
    u16* gn2eb     = au_((size_t)4096 * 512);
    u16* qkv_sa    = au_((size_t)2048 * 1536);
    u16* qkv_san   = au_((size_t)512 * 1536);
    u16* qkv_n2n   = au_((size_t)512 * 1536);
    u16* qe2eb     = au_((size_t)2048 * 512);
    u16* qn2eb     = au_((size_t)512 * 512);
    u16* kv1       = au_((size_t)4096 * 1024);
    u16* kv2       = au_((size_t)4096 * 1024);
    u16* attb_sa   = au_((size_t)2048 * 512);
    u16* attb_san  = au_((size_t)512 * 512);
    u16* attb_e2e  = au_((size_t)2048 * 512);
    u16* attb_n2e  = au_((size_t)512 * 512);
    u16* attb_n2n  = au_((size_t)512 * 512);
    u16* tmp1b     = au_((size_t)2048 * 512);
    u16* tmp1bu    = au_((size_t)512 * 512);
    u16* ffnb      = au_((size_t)2048 * 2048);
    u16* ffnbu     = au_((size_t)512 * 2048);
    u16* vtb_sa    = au_((size_t)16 * 64 * 1024);
    u16* vtb_san   = au_((size_t)16 * 64 * 256);
    u16* vtb_e2e   = au_((size_t)16 * 64 * 2048);
    u16* vtb_n2e   = au_((size_t)16 * 64 * 2048);
    u16* vtb_n2n   = au_((size_t)16 * 64 * 256);
    u16* probs_e2e = au_((size_t)16 * 1024 * 2048);
    u16* probs_n2e = au_((size_t)16 * 256 * 2048);
    u16* probs_n2n = au_((size_t)16 * 256 * 256);
    u16* wb[14];
    const int wsz[14] = {786432, 262144, 786432, 262144, 786432, 262144, 786432,
                         262144, 786432, 262144, 1048576, 1048576, 1048576, 1048576};
    for (int i = 0; i < 14; ++i) wb[i] = au_((size_t)wsz[i]);
    int* inv = (int*)(Wu + ou);

    float* out_uu = (float*)d_out;
    float* out_up = out_uu + 262144;
    float* out_w1 = out_up + 1048576;
    float* out_w2 = out_w1 + 4194304;
    float* out_w3 = out_w2 + 4194304;
    float* out_w4 = out_w3 + 1048576;

    const dim3 blk(256);

    CvtDesc cd;
    const float* wsrc[14] = {Wi_sa, Wo_sa, Wi_san, Wo_san, Wi_e2e, Wo_e2e, Wi_n2e,
                             Wo_n2e, Wi_n2n, Wo_n2n, W1, W2, W1u, W2u};
    for (int i = 0; i < 14; ++i) { cd.src[i] = wsrc[i]; cd.dst[i] = wb[i]; cd.n4[i] = wsz[i] / 4; }
    cd.src[14] = in_sp; cd.dst[14] = in_spb; cd.n4[14] = 1048576 / 4;
    cd.src[15] = in_su; cd.dst[15] = in_sub; cd.n4[15] = 262144 / 4;
    cvt_multi<<<dim3(1024, 16), blk, 0, stream>>>(cd);

    init_inv<<<16, blk, 0, stream>>>(inv);
    scatter_inv<<<4, blk, 0, stream>>>(inv, ind_pair, 1024);

    // grouped-GEMM batch builder (64-tile everywhere — round-10 verified)
    GGDesc gd{};
    int ng = 0, tot = 0;
    auto gadd = [&](const u16* A, int lda, const u16* B, int ldb,
                    float* Cf, u16* Ch, int ldc,
                    const float* bias, const float* r1,
                    float scale, int relu, int M, int N, int K) {
        gd.A[ng] = A; gd.B[ng] = B; gd.Cf[ng] = Cf; gd.Ch[ng] = Ch;
        gd.bias[ng] = bias; gd.res1[ng] = r1;
        gd.lda[ng] = lda; gd.ldb[ng] = ldb; gd.ldc[ng] = ldc;
        gd.K[ng] = K; gd.relu[ng] = relu; gd.nt[ng] = N / 64;
        gd.off[ng] = tot; gd.scale[ng] = scale;
        tot += (M / 64) * (N / 64); ++ng;
    };
    auto gflush = [&]() {
        gd.ngroups = ng;
        gg_gemm<<<tot, blk, 0, stream>>>(gd);
        ng = 0; tot = 0;
    };

    // grouped vtrans / flash / merge / avg builders
    VTDesc vd{}; int vng = 0, vtot = 0;
    auto vadd = [&](const u16* V, int ldv, u16* vT, int S) {
        vd.V[vng] = V; vd.vT[vng] = vT; vd.ldv[vng] = ldv; vd.S[vng] = S;
        vd.off[vng] = vtot; vtot += (S / 64) * 16; ++vng;
    };
    auto vflush = [&]() {
        vd.ng = vng;
        vtrans_g<<<vtot, blk, 0, stream>>>(vd);
        vng = 0; vtot = 0;
    };

    FADesc fd{}; int fng = 0, ftot = 0;
    auto fadd = [&](const u16* Q, int ldq, const u16* Kp, int ldk, const u16* vT,
                    u16* scores, float* Of, float2* pml, int L, int S, int nch) {
        fd.Q[fng] = Q; fd.Kp[fng] = Kp; fd.vT[fng] = vT; fd.scores[fng] = scores;
        fd.Of[fng] = Of; fd.pml[fng] = pml;
        fd.ldq[fng] = ldq; fd.ldk[fng] = ldk; fd.L[fng] = L; fd.S[fng] = S;
        fd.CS[fng] = S / nch; fd.off[fng] = ftot;
        ftot += (L / 64) * 16 * nch; ++fng;
    };
    auto fflush = [&](bool needW) {
        fd.ng = fng;
        if (needW) attn_flash64g<true><<<ftot, blk, 0, stream>>>(fd);
        else       attn_flash64g<false><<<ftot, blk, 0, stream>>>(fd);
        fng = 0; ftot = 0;
    };

    MGDesc md{}; int mng = 0, mtot = 0;
    auto madd = [&](const float* Of, const float2* pml, u16* att, float2* stats,
                    int L, int nch) {
        md.Of[mng] = Of; md.pml[mng] = pml; md.att[mng] = att; md.stats[mng] = stats;
        md.L[mng] = L; md.nch[mng] = nch; md.off[mng] = mtot;
        mtot += 16 * L / 4; ++mng;
    };
    auto mflush = [&]() {
        md.ng = mng;
        attn_merge_g<<<mtot, blk, 0, stream>>>(md);
        mng = 0; mtot = 0;
    };

    AVDesc ad{}; int ang = 0, atot = 0;
    auto aadd = [&](const u16* P, const float2* st, float* o1, float* o2, int L, int S) {
        ad.P[ang] = P; ad.st[ang] = st; ad.out1[ang] = o1; ad.out2[ang] = o2;
        ad.L[ang] = L; ad.S[ang] = S; ad.off[ang] = atot;
        atot += 2 * L; ++ang;
    };
    auto aflush = [&]() {
        ad.ng = ang;
        avg_softmax_g<<<atot, blk, 0, stream>>>(ad);
        ang = 0; atot = 0;
    };

    auto lnpair = [&](const float* Xa, const float* X2a, const float* ga, const float* ba,
                      float* Yfa, u16* Yba, int Ra,
                      const float* Xb, const float* X2b, const float* gb2, const float* bb2,
                      float* Yfb, u16* Ybb, int Rb) {
        LN2Desc ld;
        ld.X[0] = Xa; ld.X2[0] = X2a; ld.gam[0] = ga; ld.bet[0] = ba; ld.Yf[0] = Yfa; ld.Yb[0] = Yba;
        ld.X[1] = Xb; ld.X2[1] = X2b; ld.gam[1] = gb2; ld.bet[1] = bb2; ld.Yf[1] = Yfb; ld.Yb[1] = Ybb;
        ld.R0 = Ra;
        ln512_g<<<Ra + Rb, blk, 0, stream>>>(ld);
    };

    // ===== G1: both self-attention QKV projections =====
    gadd(in_spb, 512, wb[0], 512, nullptr, qkv_sa, 1536, bi_sa, nullptr, 1.f, 0, 2048, 1536, 512);
    gadd(in_sub, 512, wb[2], 512, nullptr, qkv_san, 1536, bi_san, nullptr, 1.f, 0, 512, 1536, 512);
    gflush();

    // ===== batch A: both self-attentions =====
    vadd(qkv_sa + 1024, 1536, vtb_sa, 1024);
    vadd(qkv_san + 1024, 1536, vtb_san, 256);
    vflush();
    fadd(qkv_sa, 1536, qkv_sa + 512, 1536, vtb_sa, nullptr, ofp_sa, pml_sa, 1024, 1024, 4);
    fadd(qkv_san, 1536, qkv_san + 512, 1536, vtb_san, nullptr, ofp_san, pml_san, 256, 256, 4);
    fflush(false);
    madd(ofp_sa, pml_sa, attb_sa, nullptr, 1024, 4);
    madd(ofp_san, pml_san, attb_san, nullptr, 256, 4);
    mflush();

    // ===== G2: both self-attention output projections =====
    gadd(attb_sa, 512, wb[1], 512, tmp0f, nullptr, 512, bo_sa, in_sp, 1.f, 0, 2048, 512, 512);
    gadd(attb_san, 512, wb[3], 512, tmp0fu, nullptr, 512, bo_san, in_su, 1.f, 0, 512, 512, 512);
    gflush();
    lnpair(tmp0f, nullptr, g1, be1, spf, spb, 2048,
           tmp0fu, nullptr, g1u, be1u, suf, sub, 512);

    // ===== gathers (one launch) =====
    gather_rows_bf2<<<dim3(2048, 2), blk, 0, stream>>>(
        ge2eb, gn2eb, spf, in_ep, ind_e2e, ind_n2e, inv, 524288);

    // ===== G3: all cross-attention input projections (5 GEMMs) =====
    gadd(spb, 512, wb[4], 512, nullptr, qe2eb, 512, bi_e2e, nullptr, 1.f, 0, 2048, 512, 512);
    gadd(ge2eb, 512, wb[4] + 262144, 512, nullptr, kv1, 1024, bi_e2e + 512, nullptr, 1.f, 0, 4096, 1024, 512);
    gadd(sub, 512, wb[6], 512, nullptr, qn2eb, 512, bi_n2e, nullptr, 1.f, 0, 512, 512, 512);
    gadd(gn2eb, 512, wb[6] + 262144, 512, nullptr, kv2, 1024, bi_n2e + 512, nullptr, 1.f, 0, 4096, 1024, 512);
    gadd(sub, 512, wb[8], 512, nullptr, qkv_n2n, 1536, bi_n2n, nullptr, 1.f, 0, 512, 1536, 512);
    gflush();

    // ===== batch B: all three weight-producing attentions (e2e 8 chunks) =====
    vadd(kv1 + 512, 1024, vtb_e2e, 2048);
    vadd(kv2 + 512, 1024, vtb_n2e, 2048);
    vadd(qkv_n2n + 1024, 1536, vtb_n2n, 256);
    vflush();
    fadd(qe2eb, 512, kv1, 1024, vtb_e2e, probs_e2e, ofp_e2e, pml_e2e, 1024, 2048, 8);
    fadd(qn2eb, 512, kv2, 1024, vtb_n2e, probs_n2e, ofp_n2e, pml_n2e, 256, 2048, 8);
    fadd(qkv_n2n, 1536, qkv_n2n + 512, 1536, vtb_n2n, probs_n2n, ofp_n2n, pml_n2n, 256, 256, 4);
    fflush(true);
    madd(ofp_e2e, pml_e2e, attb_e2e, st_e2e, 1024, 8);
    madd(ofp_n2e, pml_n2e, attb_n2e, st_n2e, 256, 8);
    madd(ofp_n2n, pml_n2n, attb_n2n, st_n2n, 256, 4);
    mflush();
    aadd(probs_e2e, st_e2e, out_w1, out_w2, 1024, 2048);
    aadd(probs_n2e, st_n2e, out_w3, nullptr, 256, 2048);
    aadd(probs_n2n, st_n2n, out_w4, nullptr, 256, 256);
    aflush();

    // ===== G4: all three output projections =====
    gadd(attb_e2e, 512, wb[5], 512, tmp0f, nullptr, 512, bo_e2e, spf, 2.f, 0, 2048, 512, 512);
    gadd(attb_n2e, 512, wb[7], 512, upn2ef, nullptr, 512, bo_n2e, nullptr, 1.f, 0, 512, 512, 512);
    gadd(attb_n2n, 512, wb[9], 512, upn2nf, nullptr, 512, bo_n2n, suf, 1.f, 0, 512, 512, 512);
    gflush();
    lnpair(tmp0f, nullptr, g2, be2, tmp1f, tmp1b, 2048,
           upn2nf, upn2ef, g2, be2, tmp1fu, tmp1bu, 512);

    // ===== G5: both FFN up-projections (relu) =====
    gadd(tmp1b, 512, wb[10], 512, nullptr, ffnb, 2048, b1f, nullptr, 1.f, 1, 2048, 2048, 512);
    gadd(tmp1bu, 512, wb[12], 512, nullptr, ffnbu, 2048, b1fu, nullptr, 1.f, 1, 512, 2048, 512);
    gflush();

    // ===== G6: both FFN down-projections (+residual) =====
    gadd(ffnb, 2048, wb[11], 2048, tmp0f, nullptr, 512, b2f, tmp1f, 1.f, 0, 2048, 512, 2048);
    gadd(ffnbu, 2048, wb[13], 2048, tmp0fu, nullptr, 512, b2fu, tmp1fu, 1.f, 0, 512, 512, 2048);
    gflush();

    lnpair(tmp0f, nullptr, g3, be3, out_up, nullptr, 2048,
           tmp0fu, nullptr, g3, be3, out_uu, nullptr, 512);
}

// Round 13
// 443.340 us; speedup vs baseline: 1.0421x; 1.0202x over previous
//
#include <hip/hip_runtime.h>
#include <cstddef>

#define LN_EPS 1e-5f

typedef unsigned short u16;
typedef short short8 __attribute__((ext_vector_type(8)));
typedef float f32x4 __attribute__((ext_vector_type(4)));

__device__ __forceinline__ u16 f2bf(float f) {
    unsigned int u = __float_as_uint(f);
    u = (u + 0x7FFFu + ((u >> 16) & 1u)) >> 16;
    return (u16)u;
}
__device__ __forceinline__ float bf2f(u16 h) {
    return __uint_as_float((unsigned int)h << 16);
}
// packed RNE f32x2 -> bf16x2 (lo = a, hi = b)
__device__ __forceinline__ unsigned int pk_bf16(float a, float b) {
    unsigned int r;
    asm("v_cvt_pk_bf16_f32 %0, %1, %2" : "=v"(r) : "v"(a), "v"(b));
    return r;
}

// ---------------------------------------------------------------------------
// Multi-tensor fp32 -> bf16 convert (weights + inputs), one launch.
// ---------------------------------------------------------------------------
struct CvtDesc {
    const float* src[16];
    u16* dst[16];
    int n4[16];
};
__global__ __launch_bounds__(256) void cvt_multi(CvtDesc d) {
    const int t = blockIdx.x * 256 + threadIdx.x;
    const int i = blockIdx.y;
    if (t >= d.n4[i]) return;
    const float4 v = ((const float4*)d.src[i])[t];
    ushort4 o;
    o.x = f2bf(v.x); o.y = f2bf(v.y); o.z = f2bf(v.z); o.w = f2bf(v.w);
    ((ushort4*)d.dst[i])[t] = o;
}

// ---------------------------------------------------------------------------
// GROUPED bf16 MFMA NT GEMM, 64x64 tile / 4 waves / BK=64 (round-10 verified
// config: with descriptor-grouping, small tiles + big uniform grids beat fat
// tiles + sparse grids — round-11 lesson). Group via prefix-offset scan.
// C = scale*(A@B^T + bias) + res1 (+relu). Outputs fp32 and/or bf16.
// ---------------------------------------------------------------------------
struct GGDesc {
    const u16* A[6]; const u16* B[6];
    float* Cf[6]; u16* Ch[6];
    const float* bias[6]; const float* res1[6];
    int lda[6], ldb[6], ldc[6], K[6], relu[6], nt[6], off[6];
    float scale[6];
    int ngroups;
};
__global__ __launch_bounds__(256) void gg_gemm(GGDesc d) {
    __shared__ u16 As[64 * 72];
    __shared__ u16 Bs[64 * 72];

    int g = 0;
    const int bid = blockIdx.x;
    while (g + 1 < d.ngroups && bid >= d.off[g + 1]) ++g;
    const int local = bid - d.off[g];
    const int m0 = (local / d.nt[g]) * 64;
    const int n0 = (local % d.nt[g]) * 64;

    const u16* __restrict__ A = d.A[g];
    const u16* __restrict__ B = d.B[g];
    const int lda = d.lda[g], ldb = d.ldb[g], ldc = d.ldc[g];
    const int K = d.K[g], relu = d.relu[g];
    const float scale = d.scale[g];

    const int tid = threadIdx.x;
    const int wave = tid >> 6, lane = tid & 63;
    const int wm = wave >> 1, wn = wave & 1;

    f32x4 acc[2][2];
#pragma unroll
    for (int mf = 0; mf < 2; ++mf)
#pragma unroll
        for (int nf = 0; nf < 2; ++nf) acc[mf][nf] = (f32x4){0.f, 0.f, 0.f, 0.f};

    const int ar = tid >> 3, ac = (tid & 7) * 8;
    const int ml = lane & 15, kq = lane >> 4;

    short8 aN[2], bN[2];
#pragma unroll
    for (int c = 0; c < 2; ++c)
        aN[c] = *(const short8*)&A[(size_t)(m0 + ar + c * 32) * lda + ac];
#pragma unroll
    for (int c = 0; c < 2; ++c)
        bN[c] = *(const short8*)&B[(size_t)(n0 + ar + c * 32) * ldb + ac];

    for (int k0 = 0; k0 < K; k0 += 64) {
        short8 aS[2], bS[2];
#pragma unroll
        for (int c = 0; c < 2; ++c) { aS[c] = aN[c]; bS[c] = bN[c]; }
        if (k0 + 64 < K) {
#pragma unroll
            for (int c = 0; c < 2; ++c)
                aN[c] = *(const short8*)&A[(size_t)(m0 + ar + c * 32) * lda + k0 + 64 + ac];
#pragma unroll
            for (int c = 0; c < 2; ++c)
                bN[c] = *(const short8*)&B[(size_t)(n0 + ar + c * 32) * ldb + k0 + 64 + ac];
        }
        __syncthreads();
#pragma unroll
        for (int c = 0; c < 2; ++c) *(short8*)&As[(ar + c * 32) * 72 + ac] = aS[c];
#pragma unroll
        for (int c = 0; c < 2; ++c) *(short8*)&Bs[(ar + c * 32) * 72 + ac] = bS[c];
        __syncthreads();

        short8 af0[2], af1[2], bf0[2], bf1[2];
#pragma unroll
        for (int mf = 0; mf < 2; ++mf) {
            const int base = (wm * 32 + mf * 16 + ml) * 72 + kq * 8;
            af0[mf] = *(const short8*)&As[base];
            af1[mf] = *(const short8*)&As[base + 32];
        }
#pragma unroll
        for (int nf = 0; nf < 2; ++nf) {
            const int base = (wn * 32 + nf * 16 + ml) * 72 + kq * 8;
            bf0[nf] = *(const short8*)&Bs[base];
            bf1[nf] = *(const short8*)&Bs[base + 32];
        }
#pragma unroll
        for (int mf = 0; mf < 2; ++mf)
#pragma unroll
            for (int nf = 0; nf < 2; ++nf) {
                acc[mf][nf] = __builtin_amdgcn_mfma_f32_16x16x32_bf16(
                    af0[mf], bf0[nf], acc[mf][nf], 0, 0, 0);
                acc[mf][nf] = __builtin_amdgcn_mfma_f32_16x16x32_bf16(
                    af1[mf], bf1[nf], acc[mf][nf], 0, 0, 0);
            }
    }

    float* __restrict__ Cf = d.Cf[g];
    u16* __restrict__ Ch = d.Ch[g];
    const float* __restrict__ bias = d.bias[g];
    const float* __restrict__ res1 = d.res1[g];
    const int rq = lane >> 4;
#pragma unroll
    for (int mf = 0; mf < 2; ++mf)
#pragma unroll
        for (int nf = 0; nf < 2; ++nf) {
            const int col = n0 + wn * 32 + nf * 16 + ml;
            const float bv = bias ? bias[col] : 0.f;
#pragma unroll
            for (int r = 0; r < 4; ++r) {
                const int row = m0 + wm * 32 + mf * 16 + rq * 4 + r;
                float v = scale * (acc[mf][nf][r] + bv);
                const size_t idx = (size_t)row * ldc + col;
                if (res1) v += res1[idx];
                if (relu) v = fmaxf(v, 0.f);
                if (Cf) Cf[idx] = v;
                if (Ch) Ch[idx] = f2bf(v);
            }
        }
}

// ---------------------------------------------------------------------------
// GROUPED V transpose (within-64 permuted layout; see attn_flash64g).
// ---------------------------------------------------------------------------
struct VTDesc {
    const u16* V[3]; u16* vT[3]; int ldv[3], S[3], off[3]; int ng;
};
__global__ __launch_bounds__(256) void vtrans_g(VTDesc d) {
    __shared__ u16 Vs[64 * 72];
    int g = 0;
    const int bid = blockIdx.x;
    while (g + 1 < d.ng && bid >= d.off[g + 1]) ++g;
    const int local = bid - d.off[g];
    const int S = d.S[g], ldv = d.ldv[g];
    const int nS = S >> 6;
    const int s0 = (local % nS) * 64;
    const int bh = local / nS, b = bh & 1, h = bh >> 1;
    const u16* __restrict__ V = d.V[g];
    u16* __restrict__ vT = d.vT[g];
    const int tid = threadIdx.x;

#pragma unroll
    for (int c = 0; c < 2; ++c) {
        const int idx = tid + c * 256;
        const int sr = idx >> 3, dc = (idx & 7) * 8;
        *(short8*)&Vs[sr * 72 + dc] =
            *(const short8*)&V[(size_t)((s0 + sr) * 2 + b) * ldv + h * 64 + dc];
    }
    __syncthreads();
#pragma unroll
    for (int c = 0; c < 2; ++c) {
        const int idx = tid + c * 256;
        const int dr = idx >> 3, sc = (idx & 7) * 8;
        short8 o;
#pragma unroll
        for (int j = 0; j < 8; ++j) {
            const int p = sc + j;
            o[j] = (short)Vs[((p >> 2) + 16 * (p & 3)) * 72 + dr];
        }
        *(short8*)&vT[(size_t)bh * 64 * S + (size_t)dr * S + s0 + sc] = o;
    }
}

// ---------------------------------------------------------------------------
// GROUPED split-S flash attention (round-8 verified body, descriptor-batched;
// up to 3 independent attentions per launch). Separate merge kernel (stream
// boundary provides cross-block ordering — NO device fences, round-7 lesson).
// ---------------------------------------------------------------------------
struct FADesc {
    const u16* Q[3]; const u16* Kp[3]; const u16* vT[3]; u16* scores[3];
    float* Of[3]; float2* pml[3];
    int ldq[3], ldk[3], L[3], S[3], CS[3], off[3];
    int ng;
};
template<bool NEED_W>
__global__ __launch_bounds__(256) void attn_flash64g(FADesc d) {
    __shared__ u16 Ks[64 * 72];
    __shared__ u16 Vt[64 * 72];
    __shared__ u16 St[4][16 * 72];

    int g = 0;
    const int bid = blockIdx.x;
    while (g + 1 < d.ng && bid >= d.off[g + 1]) ++g;
    int local = bid - d.off[g];
    const int L = d.L[g], S = d.S[g], CS = d.CS[g];
    const int ldq = d.ldq[g], ldk = d.ldk[g];
    const int nx = L >> 6;
    const int bx = local % nx; local /= nx;
    const int bz = local & 15;
    const int chunk = local >> 4;

    const u16* __restrict__ Q = d.Q[g];
    const u16* __restrict__ Kp = d.Kp[g];
    const u16* __restrict__ vT = d.vT[g];
    float* __restrict__ Of = d.Of[g];
    float2* __restrict__ pml = d.pml[g];

    const int tid = threadIdx.x;
    const int wave = tid >> 6, lane = tid & 63;
    const int ml = lane & 15, rq = lane >> 4;
    const int i0 = bx * 64;
    const int bb = bz & 1, hh = bz >> 1;
    const int cs0 = chunk * CS;
    u16* Sb = NEED_W ? d.scores[g] + (size_t)bz * L * S + (size_t)i0 * S : nullptr;
    const u16* Vbase = vT + (size_t)bz * 64 * S;

    const int qrow = i0 + wave * 16 + ml;
    const short8 qf0 = *(const short8*)&Q[(size_t)(qrow * 2 + bb) * ldq + hh * 64 + rq * 8];
    const short8 qf1 = *(const short8*)&Q[(size_t)(qrow * 2 + bb) * ldq + hh * 64 + 32 + rq * 8];

    float mrun[4], lrun[4];
    f32x4 acc[4];
#pragma unroll
    for (int r = 0; r < 4; ++r) {
        mrun[r] = -1e30f; lrun[r] = 0.f;
        acc[r] = (f32x4){0.f, 0.f, 0.f, 0.f};
    }

    const int sr0 = tid >> 3, dc0 = (tid & 7) * 8;
    const int sr1 = (tid + 256) >> 3, dc1 = ((tid + 256) & 7) * 8;

    short8 kr0 = *(const short8*)&Kp[(size_t)((cs0 + sr0) * 2 + bb) * ldk + hh * 64 + dc0];
    short8 kr1 = *(const short8*)&Kp[(size_t)((cs0 + sr1) * 2 + bb) * ldk + hh * 64 + dc1];
    short8 vr0 = *(const short8*)&Vbase[(size_t)sr0 * S + cs0 + dc0];
    short8 vr1 = *(const short8*)&Vbase[(size_t)sr1 * S + cs0 + dc1];

    u16* Sw = St[wave];

    for (int k0 = cs0; k0 < cs0 + CS; k0 += 64) {
        __syncthreads();
        *(short8*)&Ks[sr0 * 72 + dc0] = kr0;
        *(short8*)&Ks[sr1 * 72 + dc1] = kr1;
        *(short8*)&Vt[sr0 * 72 + dc0] = vr0;
        *(short8*)&Vt[sr1 * 72 + dc1] = vr1;
        if (k0 + 64 < cs0 + CS) {
            const int kn = k0 + 64;
            kr0 = *(const short8*)&Kp[(size_t)((kn + sr0) * 2 + bb) * ldk + hh * 64 + dc0];
            kr1 = *(const short8*)&Kp[(size_t)((kn + sr1) * 2 + bb) * ldk + hh * 64 + dc1];
            vr0 = *(const short8*)&Vbase[(size_t)sr0 * S + kn + dc0];
            vr1 = *(const short8*)&Vbase[(size_t)sr1 * S + kn + dc1];
        }
        __syncthreads();

        f32x4 sc[4];
#pragma unroll
        for (int nf = 0; nf < 4; ++nf) {
            const short8 kf0 = *(const short8*)&Ks[(nf * 16 + ml) * 72 + rq * 8];
            const short8 kf1 = *(const short8*)&Ks[(nf * 16 + ml) * 72 + 32 + rq * 8];
            f32x4 s = (f32x4){0.f, 0.f, 0.f, 0.f};
            s = __builtin_amdgcn_mfma_f32_16x16x32_bf16(qf0, kf0, s, 0, 0, 0);
            s = __builtin_amdgcn_mfma_f32_16x16x32_bf16(qf1, kf1, s, 0, 0, 0);
#pragma unroll
            for (int r = 0; r < 4; ++r) s[r] *= 0.125f;
            sc[nf] = s;
        }

        if (NEED_W) {
#pragma unroll
            for (int r = 0; r < 4; ++r) {
                const unsigned int pk0 = pk_bf16(sc[0][r], sc[1][r]);
                const unsigned int pk1 = pk_bf16(sc[2][r], sc[3][r]);
                *(uint2*)&Sb[(size_t)(wave * 16 + rq * 4 + r) * S + k0 + ml * 4] =
                    make_uint2(pk0, pk1);
            }
        }

        float tm[4];
#pragma unroll
        for (int r = 0; r < 4; ++r)
            tm[r] = fmaxf(fmaxf(sc[0][r], sc[1][r]), fmaxf(sc[2][r], sc[3][r]));
#pragma unroll
        for (int mk = 1; mk < 16; mk <<= 1)
#pragma unroll
            for (int r = 0; r < 4; ++r)
                tm[r] = fmaxf(tm[r], __shfl_xor(tm[r], mk));

        float alpha[4], mn[4];
#pragma unroll
        for (int r = 0; r < 4; ++r) {
            mn[r] = fmaxf(mrun[r], tm[r]);
            alpha[r] = __expf(mrun[r] - mn[r]);
            mrun[r] = mn[r];
        }

        float rs[4];
#pragma unroll
        for (int r = 0; r < 4; ++r) {
            const float p0 = __expf(sc[0][r] - mn[r]);
            const float p1 = __expf(sc[1][r] - mn[r]);
            const float p2 = __expf(sc[2][r] - mn[r]);
            const float p3 = __expf(sc[3][r] - mn[r]);
            rs[r] = (p0 + p1) + (p2 + p3);
            const unsigned int pk0 = pk_bf16(p0, p1);
            const unsigned int pk1 = pk_bf16(p2, p3);
            *(uint2*)&Sw[(rq * 4 + r) * 72 + ml * 4] = make_uint2(pk0, pk1);
        }
#pragma unroll
        for (int mk = 1; mk < 16; mk <<= 1)
#pragma unroll
            for (int r = 0; r < 4; ++r)
                rs[r] += __shfl_xor(rs[r], mk);
#pragma unroll
        for (int r = 0; r < 4; ++r)
            lrun[r] = lrun[r] * alpha[r] + rs[r];

#pragma unroll
        for (int df = 0; df < 4; ++df)
#pragma unroll
            for (int r = 0; r < 4; ++r)
                acc[df][r] *= alpha[r];
#pragma unroll
        for (int kc = 0; kc < 2; ++kc) {
            const short8 afr = *(const short8*)&Sw[ml * 72 + kc * 32 + rq * 8];
#pragma unroll
            for (int df = 0; df < 4; ++df) {
                const short8 bfr = *(const short8*)&Vt[(df * 16 + ml) * 72 + kc * 32 + rq * 8];
                acc[df] = __builtin_amdgcn_mfma_f32_16x16x32_bf16(afr, bfr, acc[df], 0, 0, 0);
            }
        }
    }

#pragma unroll
    for (int df = 0; df < 4; ++df)
#pragma unroll
        for (int r = 0; r < 4; ++r) {
            const int i = i0 + wave * 16 + rq * 4 + r;
            Of[((size_t)(chunk * 16 + bz) * L + i) * 64 + df * 16 + ml] = acc[df][r];
        }
    if (ml == 0) {
#pragma unroll
        for (int r = 0; r < 4; ++r)
            pml[(size_t)chunk * 16 * L + (size_t)bz * L + i0 + wave * 16 + rq * 4 + r] =
                make_float2(mrun[r], lrun[r]);
    }
}

// ---------------------------------------------------------------------------
// GROUPED merge of split-S partials. stats written iff stats[g] != null.
// ---------------------------------------------------------------------------
struct MGDesc {
    const float* Of[3]; const float2* pml[3]; u16* att[3]; float2* stats[3];
    int L[3], nch[3], off[3]; int ng;
};
__global__ __launch_bounds__(256) void attn_merge_g(MGDesc d) {
    int gg = 0;
    const int bid = blockIdx.x;
    while (gg + 1 < d.ng && bid >= d.off[gg + 1]) ++gg;
    const int local = bid - d.off[gg];
    const int L = d.L[gg], nchunks = d.nch[gg];
    const float* __restrict__ Of = d.Of[gg];
    const float2* __restrict__ pml = d.pml[gg];

    const int tid = threadIdx.x;
    const int grow = local * 4 + (tid >> 6);
    const int dcol = tid & 63;
    const int bz = grow / L, i = grow - bz * L;
    const int bb = bz & 1, hh = bz >> 1;

    float M = -1e30f;
    for (int c = 0; c < nchunks; ++c)
        M = fmaxf(M, pml[(size_t)c * 16 * L + grow].x);
    float T = 0.f, O = 0.f;
    for (int c = 0; c < nchunks; ++c) {
        const float2 w2 = pml[(size_t)c * 16 * L + grow];
        const float w = __expf(w2.x - M);
        T += w2.y * w;
        O += w * Of[((size_t)(c * 16 + bz) * L + i) * 64 + dcol];
    }
    const float invT = 1.0f / T;
    d.att[gg][((size_t)i * 2 + bb) * 512 + hh * 64 + dcol] = f2bf(O * invT);
    if (d.stats[gg] && dcol == 0)
        d.stats[gg][(size_t)bz * L + i] = make_float2(M, invT);
}

// ---------------------------------------------------------------------------
// GROUPED head-average + second softmax. probs permuted-within-64; un-permute
// via LDS, coalesced float4 final writes.
// ---------------------------------------------------------------------------
struct AVDesc {
    const u16* P[3]; const float2* st[3]; float* out1[3]; float* out2[3];
    int L[3], S[3], off[3]; int ng;
};
__global__ __launch_bounds__(256) void avg_softmax_g(AVDesc d) {
    __shared__ float red[256];
    __shared__ float stage[2048];
    int g = 0;
    const int bid = blockIdx.x;
    while (g + 1 < d.ng && bid >= d.off[g + 1]) ++g;
    const int local = bid - d.off[g];
    const int L = d.L[g], S = d.S[g];
    const int b = local / L, i = local % L;
    const u16* __restrict__ P = d.P[g];
    const float2* __restrict__ st = d.st[g];
    const size_t LS = (size_t)L * S;
    const int tid = threadIdx.x;
    const bool act = tid * 8 < S;

    float acc[8] = {};
    if (act) {
#pragma unroll
        for (int h = 0; h < 8; ++h) {
            const int bh = h * 2 + b;
            const float2 s = st[(size_t)bh * L + i];
            const short8 r8 = *(const short8*)&P[(size_t)bh * LS + (size_t)i * S + tid * 8];
#pragma unroll
            for (int j = 0; j < 8; ++j)
                acc[j] += __expf(bf2f((u16)r8[j]) - s.x) * s.y;
        }
#pragma unroll
        for (int j = 0; j < 8; ++j) acc[j] *= 0.125f;
    }
    float lmax = -1e30f;
    if (act) {
#pragma unroll
        for (int j = 0; j < 8; ++j) lmax = fmaxf(lmax, acc[j]);
    }
    red[tid] = lmax; __syncthreads();
    for (int s = 128; s; s >>= 1) {
        if (tid < s) red[tid] = fmaxf(red[tid], red[tid + s]);
        __syncthreads();
    }
    const float mx = red[0]; __syncthreads();
    float e[8];
    float ls = 0.f;
    if (act) {
#pragma unroll
        for (int j = 0; j < 8; ++j) { e[j] = __expf(acc[j] - mx); ls += e[j]; }
    }
    red[tid] = ls; __syncthreads();
    for (int s = 128; s; s >>= 1) {
        if (tid < s) red[tid] += red[tid + s];
        __syncthreads();
    }
    const float inv = 1.0f / red[0];
    if (act) {
        const int g64 = (tid >> 3) * 64;
        const int t2 = (tid & 7) * 2;
#pragma unroll
        for (int j = 0; j < 8; ++j) {
            const int c = t2 + (j >> 2) + 16 * (j & 3);
            stage[g64 + c] = e[j] * inv;
        }
    }
    __syncthreads();
    float* out1 = d.out1[g];
    float* out2 = d.out2[g];
    const size_t base = (size_t)local * S;
    for (int idx = tid * 4; idx < S; idx += 1024) {
        const float4 v = *(const float4*)&stage[idx];
        *(float4*)&out1[base + idx] = v;
        if (out2) *(float4*)&out2[base + idx] = v;
    }
}

// ---------------------------------------------------------------------------
// LayerNorm over rows of 512 of (X + optional X2); PAIRED: two groups per
// launch (blockIdx < R0 -> group 0).
// ---------------------------------------------------------------------------
struct LN2Desc {
    const float* X[2]; const float* X2[2];
    const float* gam[2]; const float* bet[2];
    float* Yf[2]; u16* Yb[2]; int R0;
};
__global__ __launch_bounds__(256) void ln512_g(LN2Desc d) {
    __shared__ float red[256];
    const int gi = (blockIdx.x < (unsigned)d.R0) ? 0 : 1;
    const int r = gi ? (blockIdx.x - d.R0) : blockIdx.x;
    const int tid = threadIdx.x;
    const float* xr = d.X[gi] + (size_t)r * 512;
    float x0 = xr[tid], x1 = xr[tid + 256];
    if (d.X2[gi]) {
        const float* x2r = d.X2[gi] + (size_t)r * 512;
        x0 += x2r[tid]; x1 += x2r[tid + 256];
    }
    red[tid] = x0 + x1; __syncthreads();
    for (int st = 128; st; st >>= 1) {
        if (tid < st) red[tid] += red[tid + st];
        __syncthreads();
    }
    const float mean = red[0] * (1.0f / 512.0f); __syncthreads();
    const float d0 = x0 - mean, d1 = x1 - mean;
    red[tid] = d0 * d0 + d1 * d1; __syncthreads();
    for (int st = 128; st; st >>= 1) {
        if (tid < st) red[tid] += red[tid + st];
        __syncthreads();
    }
    const float rstd = rsqrtf(red[0] * (1.0f / 512.0f) + LN_EPS);
    const float y0 = d0 * rstd * d.gam[gi][tid] + d.bet[gi][tid];
    const float y1 = d1 * rstd * d.gam[gi][tid + 256] + d.bet[gi][tid + 256];
    float* yr = d.Yf[gi] + (size_t)r * 512;
    yr[tid] = y0; yr[tid + 256] = y1;
    if (d.Yb[gi]) {
        u16* yb = d.Yb[gi] + (size_t)r * 512;
        yb[tid] = f2bf(y0); yb[tid + 256] = f2bf(y1);
    }
}

// ---------------------------------------------------------------------------
// pair assembly: inverse map + gathers (both destinations in one launch).
// ---------------------------------------------------------------------------
__global__ void init_inv(int* __restrict__ inv) {
    const int i = blockIdx.x * 256 + threadIdx.x;
    if (i < 4096) inv[i] = -1;
}
__global__ void scatter_inv(int* __restrict__ inv, const int* __restrict__ ind, int n) {
    const int i = blockIdx.x * 256 + threadIdx.x;
    if (i < n) inv[ind[i]] = i;
}
__global__ void gather_rows_bf2(
    u16* __restrict__ dst0, u16* __restrict__ dst1,
    const float* __restrict__ spf, const float* __restrict__ ep,
    const int* __restrict__ ind0, const int* __restrict__ ind1,
    const int* __restrict__ inv, int total4)
{
    const int e = blockIdx.x * 256 + threadIdx.x;
    if (e >= total4) return;
    u16* dst = blockIdx.y ? dst1 : dst0;
    const int* ind = blockIdx.y ? ind1 : ind0;
    const int row = e >> 7, c = e & 127;
    const int j = row >> 1, b = row & 1;
    const int idx = ind[j];
    const int iv = inv[idx];
    const float4* src = (iv >= 0) ? (const float4*)(spf + (size_t)(iv * 2 + b) * 512)
                                  : (const float4*)(ep + (size_t)(idx * 2 + b) * 512);
    const float4 v = src[c];
    ushort4 o; o.x = f2bf(v.x); o.y = f2bf(v.y); o.z = f2bf(v.z); o.w = f2bf(v.w);
    ((ushort4*)dst)[e] = o;
}

// ---------------------------------------------------------------------------
extern "C" void kernel_launch(void* const* d_in, const int* in_sizes, int n_in,
                              void* d_out, int out_size, void* d_ws, size_t ws_size,
                              hipStream_t stream)
{
    (void)in_sizes; (void)n_in; (void)out_size; (void)ws_size;

    const float* in_sp = (const float*)d_in[0];
    const float* in_su = (const float*)d_in[1];
    const float* in_ep = (const float*)d_in[2];
    const int* ind_pair = (const int*)d_in[3];
    const int* ind_e2e  = (const int*)d_in[4];
    const int* ind_n2e  = (const int*)d_in[5];
    const float *Wi_sa  = (const float*)d_in[6],  *bi_sa  = (const float*)d_in[7];
    const float *Wo_sa  = (const float*)d_in[8],  *bo_sa  = (const float*)d_in[9];
    const float *Wi_san = (const float*)d_in[10], *bi_san = (const float*)d_in[11];
    const float *Wo_san = (const float*)d_in[12], *bo_san = (const float*)d_in[13];
    const float *Wi_e2e = (const float*)d_in[14], *bi_e2e = (const float*)d_in[15];
    const float *Wo_e2e = (const float*)d_in[16], *bo_e2e = (const float*)d_in[17];
    const float *Wi_n2e = (const float*)d_in[18], *bi_n2e = (const float*)d_in[19];
    const float *Wo_n2e = (const float*)d_in[20], *bo_n2e = (const float*)d_in[21];
    const float *Wi_n2n = (const float*)d_in[22], *bi_n2n = (const float*)d_in[23];
    const float *Wo_n2n = (const float*)d_in[24], *bo_n2n = (const float*)d_in[25];
    const float *W1  = (const float*)d_in[26], *b1f  = (const float*)d_in[27];
    const float *W2  = (const float*)d_in[28], *b2f  = (const float*)d_in[29];
    const float *W1u = (const float*)d_in[30], *b1fu = (const float*)d_in[31];
    const float *W2u = (const float*)d_in[32], *b2fu = (const float*)d_in[33];
    const float *g1  = (const float*)d_in[34], *g1u = (const float*)d_in[35];
    const float *g2  = (const float*)d_in[36], *g3  = (const float*)d_in[37];
    const float *be1 = (const float*)d_in[38], *be1u = (const float*)d_in[39];
    const float *be2 = (const float*)d_in[40], *be3  = (const float*)d_in[41];

    float* Wf = (float*)d_ws;
    size_t of = 0;
    auto af_ = [&](size_t n) { float* p = Wf + of; of += n; return p; };
    float* spf      = af_((size_t)2048 * 512);
    float* suf      = af_((size_t)512 * 512);
    float* tmp0f    = af_((size_t)2048 * 512);
    float* tmp0fu   = af_((size_t)512 * 512);
    float* upn2ef   = af_((size_t)512 * 512);
    float* upn2nf   = af_((size_t)512 * 512);
    float* tmp1f    = af_((size_t)2048 * 512);
    float* tmp1fu   = af_((size_t)512 * 512);
    float2* st_e2e  = (float2*)af_((size_t)2 * 16 * 1024);
    float2* st_n2e  = (float2*)af_((size_t)2 * 16 * 256);
    float2* st_n2n  = (float2*)af_((size_t)2 * 16 * 256);
    float* ofp_sa   = af_((size_t)4 * 16 * 1024 * 64);
    float* ofp_san  = af_((size_t)4 * 16 * 256 * 64);
    float* ofp_e2e  = af_((size_t)4 * 16 * 1024 * 64);
    float* ofp_n2e  = af_((size_t)8 * 16 * 256 * 64);
    float* ofp_n2n  = af_((size_t)4 * 16 * 256 * 64);
    float2* pml_sa  = (float2*)af_((size_t)2 * 4 * 16 * 1024);
    float2* pml_san = (float2*)af_((size_t)2 * 4 * 16 * 256);
    float2* pml_e2e = (float2*)af_((size_t)2 * 4 * 16 * 1024);
    float2* pml_n2e = (float2*)af_((size_t)2 * 8 * 16 * 256);
    float2* pml_n2n = (float2*)af_((size_t)2 * 4 * 16 * 256);

    u16* Wu = (u16*)(Wf + of);
    size_t ou = 0;
    auto au_ = [&](size_t n) { u16* p = Wu + ou; ou += n; return p; };
    u16* in_spb    = au_((size_t)2048 * 512);
    u16* in_sub    = au_((size_t)512 * 512);
    u16* spb       = au_((size_t)2048 * 512);
    u16* sub       = au_((size_t)512 * 512);
    u16* ge2eb     = au_((size_t)4096 * 512);
    u16* gn2eb     = au_((size_t)4096 * 512);
    u16* qkv_sa    = au_((size_t)2048 * 1536);
    u16* qkv_san   = au_((size_t)512 * 1536);
    u16* qkv_n2n   = au_((size_t)512 * 1536);
    u16* qe2eb     = au_((size_t)2048 * 512);
    u16* qn2eb     = au_((size_t)512 * 512);
    u16* kv1       = au_((size_t)4096 * 1024);
    u16* kv2       = au_((size_t)4096 * 1024);
    u16* attb_sa   = au_((size_t)2048 * 512);
    u16* attb_san  = au_((size_t)512 * 512);
    u16* attb_e2e  = au_((size_t)2048 * 512);
    u16* attb_n2e  = au_((size_t)512 * 512);
    u16* attb_n2n  = au_((size_t)512 * 512);
    u16* tmp1b     = au_((size_t)2048 * 512);
    u16* tmp1bu    = au_((size_t)512 * 512);
    u16* ffnb      = au_((size_t)2048 * 2048);
    u16* ffnbu     = au_((size_t)512 * 2048);
    u16* vtb_sa    = au_((size_t)16 * 64 * 1024);
    u16* vtb_san   = au_((size_t)16 * 64 * 256);
    u16* vtb_e2e   = au_((size_t)16 * 64 * 2048);
    u16* vtb_n2e   = au_((size_t)16 * 64 * 2048);
    u16* vtb_n2n   = au_((size_t)16 * 64 * 256);
    u16* probs_e2e = au_((size_t)16 * 1024 * 2048);
    u16* probs_n2e = au_((size_t)16 * 256 * 2048);
    u16* probs_n2n = au_((size_t)16 * 256 * 256);
    u16* wb[14];
    const int wsz[14] = {786432, 262144, 786432, 262144, 786432, 262144, 786432,
                         262144, 786432, 262144, 1048576, 1048576, 1048576, 1048576};
    for (int i = 0; i < 14; ++i) wb[i] = au_((size_t)wsz[i]);
    int* inv = (int*)(Wu + ou);

    float* out_uu = (float*)d_out;
    float* out_up = out_uu + 262144;
    float* out_w1 = out_up + 1048576;
    float* out_w2 = out_w1 + 4194304;
    float* out_w3 = out_w2 + 4194304;
    float* out_w4 = out_w3 + 1048576;

    const dim3 blk(256);

    CvtDesc cd;
    const float* wsrc[14] = {Wi_sa, Wo_sa, Wi_san, Wo_san, Wi_e2e, Wo_e2e, Wi_n2e,
                             Wo_n2e, Wi_n2n, Wo_n2n, W1, W2, W1u, W2u};
    for (int i = 0; i < 14; ++i) { cd.src[i] = wsrc[i]; cd.dst[i] = wb[i]; cd.n4[i] = wsz[i] / 4; }
    cd.src[14] = in_sp; cd.dst[14] = in_spb; cd.n4[14] = 1048576 / 4;
    cd.src[15] = in_su; cd.dst[15] = in_sub; cd.n4[15] = 262144 / 4;
    cvt_multi<<<dim3(1024, 16), blk, 0, stream>>>(cd);

    init_inv<<<16, blk, 0, stream>>>(inv);
    scatter_inv<<<4, blk, 0, stream>>>(inv, ind_pair, 1024);

    // grouped-GEMM batch builder (64-tile everywhere — round-10 verified)
    GGDesc gd{};
    int ng = 0, tot = 0;
    auto gadd = [&](const u16* A, int lda, const u16* B, int ldb,
                    float* Cf, u16* Ch, int ldc,
                    const float* bias, const float* r1,
                    float scale, int relu, int M, int N, int K) {
        gd.A[ng] = A; gd.B[ng] = B; gd.Cf[ng] = Cf; gd.Ch[ng] = Ch;
        gd.bias[ng] = bias; gd.res1[ng] = r1;
        gd.lda[ng] = lda; gd.ldb[ng] = ldb; gd.ldc[ng] = ldc;
        gd.K[ng] = K; gd.relu[ng] = relu; gd.nt[ng] = N / 64;
        gd.off[ng] = tot; gd.scale[ng] = scale;
        tot += (M / 64) * (N / 64); ++ng;
    };
    auto gflush = [&]() {
        gd.ngroups = ng;
        gg_gemm<<<tot, blk, 0, stream>>>(gd);
        ng = 0; tot = 0;
    };

    // grouped vtrans / flash / merge / avg builders
    VTDesc vd{}; int vng = 0, vtot = 0;
    auto vadd = [&](const u16* V, int ldv, u16* vT, int S) {
        vd.V[vng] = V; vd.vT[vng] = vT; vd.ldv[vng] = ldv; vd.S[vng] = S;
        vd.off[vng] = vtot; vtot += (S / 64) * 16; ++vng;
    };
    auto vflush = [&]() {
        vd.ng = vng;
        vtrans_g<<<vtot, blk, 0, stream>>>(vd);
        vng = 0; vtot = 0;
    };

    FADesc fd{}; int fng = 0, ftot = 0;
    auto fadd = [&](const u16* Q, int ldq, const u16* Kp, int ldk, const u16* vT,
                    u16* scores, float* Of, float2* pml, int L, int S, int nch) {
        fd.Q[fng] = Q; fd.Kp[fng] = Kp; fd.vT[fng] = vT; fd.scores[fng] = scores;
        fd.Of[fng] = Of; fd.pml[fng] = pml;
        fd.ldq[fng] = ldq; fd.ldk[fng] = ldk; fd.L[fng] = L; fd.S[fng] = S;
        fd.CS[fng] = S / nch; fd.off[fng] = ftot;
        ftot += (L / 64) * 16 * nch; ++fng;
    };
    auto fflush = [&](bool needW) {
        fd.ng = fng;
        if (needW) attn_flash64g<true><<<ftot, blk, 0, stream>>>(fd);
        else       attn_flash64g<false><<<ftot, blk, 0, stream>>>(fd);
        fng = 0; ftot = 0;
    };

    MGDesc md{}; int mng = 0, mtot = 0;
    auto madd = [&](const float* Of, const float2* pml, u16* att, float2* stats,
                    int L, int nch) {
        md.Of[mng] = Of; md.pml[mng] = pml; md.att[mng] = att; md.stats[mng] = stats;
        md.L[mng] = L; md.nch[mng] = nch; md.off[mng] = mtot;
        mtot += 16 * L / 4; ++mng;
    };
    auto mflush = [&]() {
        md.ng = mng;
        attn_merge_g<<<mtot, blk, 0, stream>>>(md);
        mng = 0; mtot = 0;
    };

    AVDesc ad{}; int ang = 0, atot = 0;
    auto aadd = [&](const u16* P, const float2* st, float* o1, float* o2, int L, int S) {
        ad.P[ang] = P; ad.st[ang] = st; ad.out1[ang] = o1; ad.out2[ang] = o2;
        ad.L[ang] = L; ad.S[ang] = S; ad.off[ang] = atot;
        atot += 2 * L; ++ang;
    };
    auto aflush = [&]() {
        ad.ng = ang;
        avg_softmax_g<<<atot, blk, 0, stream>>>(ad);
        ang = 0; atot = 0;
    };

    auto lnpair = [&](const float* Xa, const float* X2a, const float* ga, const float* ba,
                      float* Yfa, u16* Yba, int Ra,
                      const float* Xb, const float* X2b, const float* gb2, const float* bb2,
                      float* Yfb, u16* Ybb, int Rb) {
        LN2Desc ld;
        ld.X[0] = Xa; ld.X2[0] = X2a; ld.gam[0] = ga; ld.bet[0] = ba; ld.Yf[0] = Yfa; ld.Yb[0] = Yba;
        ld.X[1] = Xb; ld.X2[1] = X2b; ld.gam[1] = gb2; ld.bet[1] = bb2; ld.Yf[1] = Yfb; ld.Yb[1] = Ybb;
        ld.R0 = Ra;
        ln512_g<<<Ra + Rb, blk, 0, stream>>>(ld);
    };

    // ===== G1: both self-attention QKV projections =====
    gadd(in_spb, 512, wb[0], 512, nullptr, qkv_sa, 1536, bi_sa, nullptr, 1.f, 0, 2048, 1536, 512);
    gadd(in_sub, 512, wb[2], 512, nullptr, qkv_san, 1536, bi_san, nullptr, 1.f, 0, 512, 1536, 512);
    gflush();

    // ===== batch A: both self-attentions =====
    vadd(qkv_sa + 1024, 1536, vtb_sa, 1024);
    vadd(qkv_san + 1024, 1536, vtb_san, 256);
    vflush();
    fadd(qkv_sa, 1536, qkv_sa + 512, 1536, vtb_sa, nullptr, ofp_sa, pml_sa, 1024, 1024, 4);
    fadd(qkv_san, 1536, qkv_san + 512, 1536, vtb_san, nullptr, ofp_san, pml_san, 256, 256, 4);
    fflush(false);
    madd(ofp_sa, pml_sa, attb_sa, nullptr, 1024, 4);
    madd(ofp_san, pml_san, attb_san, nullptr, 256, 4);
    mflush();

    // ===== G2: both self-attention output projections =====
    gadd(attb_sa, 512, wb[1], 512, tmp0f, nullptr, 512, bo_sa, in_sp, 1.f, 0, 2048, 512, 512);
    gadd(attb_san, 512, wb[3], 512, tmp0fu, nullptr, 512, bo_san, in_su, 1.f, 0, 512, 512, 512);
    gflush();
    lnpair(tmp0f, nullptr, g1, be1, spf, spb, 2048,
           tmp0fu, nullptr, g1u, be1u, suf, sub, 512);

    // ===== gathers (one launch) =====
    gather_rows_bf2<<<dim3(2048, 2), blk, 0, stream>>>(
        ge2eb, gn2eb, spf, in_ep, ind_e2e, ind_n2e, inv, 524288);

    // ===== G3: all cross-attention input projections (5 GEMMs) =====
    gadd(spb, 512, wb[4], 512, nullptr, qe2eb, 512, bi_e2e, nullptr, 1.f, 0, 2048, 512, 512);
    gadd(ge2eb, 512, wb[4] + 262144, 512, nullptr, kv1, 1024, bi_e2e + 512, nullptr, 1.f, 0, 4096, 1024, 512);
    gadd(sub, 512, wb[6], 512, nullptr, qn2eb, 512, bi_n2e, nullptr, 1.f, 0, 512, 512, 512);
    gadd(gn2eb, 512, wb[6] + 262144, 512, nullptr, kv2, 1024, bi_n2e + 512, nullptr, 1.f, 0, 4096, 1024, 512);
    gadd(sub, 512, wb[8], 512, nullptr, qkv_n2n, 1536, bi_n2n, nullptr, 1.f, 0, 512, 1536, 512);
    gflush();

    // ===== batch B: all three weight-producing attentions (round-10 chunks) =====
    vadd(kv1 + 512, 1024, vtb_e2e, 2048);
    vadd(kv2 + 512, 1024, vtb_n2e, 2048);
    vadd(qkv_n2n + 1024, 1536, vtb_n2n, 256);
    vflush();
    fadd(qe2eb, 512, kv1, 1024, vtb_e2e, probs_e2e, ofp_e2e, pml_e2e, 1024, 2048, 4);
    fadd(qn2eb, 512, kv2, 1024, vtb_n2e, probs_n2e, ofp_n2e, pml_n2e, 256, 2048, 8);
    fadd(qkv_n2n, 1536, qkv_n2n + 512, 1536, vtb_n2n, probs_n2n, ofp_n2n, pml_n2n, 256, 256, 4);
    fflush(true);
    madd(ofp_e2e, pml_e2e, attb_e2e, st_e2e, 1024, 4);
    madd(ofp_n2e, pml_n2e, attb_n2e, st_n2e, 256, 8);
    madd(ofp_n2n, pml_n2n, attb_n2n, st_n2n, 256, 4);
    mflush();
    aadd(probs_e2e, st_e2e, out_w1, out_w2, 1024, 2048);
    aadd(probs_n2e, st_n2e, out_w3, nullptr, 256, 2048);
    aadd(probs_n2n, st_n2n, out_w4, nullptr, 256, 256);
    aflush();

    // ===== G4: all three output projections =====
    gadd(attb_e2e, 512, wb[5], 512, tmp0f, nullptr, 512, bo_e2e, spf, 2.f, 0, 2048, 512, 512);
    gadd(attb_n2e, 512, wb[7], 512, upn2ef, nullptr, 512, bo_n2e, nullptr, 1.f, 0, 512, 512, 512);
    gadd(attb_n2n, 512, wb[9], 512, upn2nf, nullptr, 512, bo_n2n, suf, 1.f, 0, 512, 512, 512);
    gflush();
    lnpair(tmp0f, nullptr, g2, be2, tmp1f, tmp1b, 2048,
           upn2nf, upn2ef, g2, be2, tmp1fu, tmp1bu, 512);

    // ===== G5: both FFN up-projections (relu) =====
    gadd(tmp1b, 512, wb[10], 512, nullptr, ffnb, 2048, b1f, nullptr, 1.f, 1, 2048, 2048, 512);
    gadd(tmp1bu, 512, wb[12], 512, nullptr, ffnbu, 2048, b1fu, nullptr, 1.f, 1, 512, 2048, 512);
    gflush();

    // ===== G6: both FFN down-projections (+residual) =====
    gadd(ffnb, 2048, wb[11], 2048, tmp0f, nullptr, 512, b2f, tmp1f, 1.f, 0, 2048, 512, 2048);
    gadd(ffnbu, 2048, wb[13], 2048, tmp0fu, nullptr, 512, b2fu, tmp1fu, 1.f, 0, 512, 512, 2048);
    gflush();

    lnpair(tmp0f, nullptr, g3, be3, out_up, nullptr, 2048,
           tmp0fu, nullptr, g3, be3, out_uu, nullptr, 512);
}